// Round 12
// baseline (619.901 us; speedup 1.0000x reference)
//
#include <hip/hip_runtime.h>
#include <hip/hip_bf16.h>
#include <cstdint>
#include <cstddef>

typedef __attribute__((ext_vector_type(8))) _Float16 f16x8;
typedef __attribute__((ext_vector_type(4))) float f32x4;

#define KPAD2 2432
#define NT2 38

__device__ __forceinline__ float h2f(unsigned short u) {
  union { unsigned short s; _Float16 h; } x; x.s = u; return (float)x.h;
}
__device__ __forceinline__ unsigned short f2h(float f) {
  union { unsigned short s; _Float16 h; } x; x.h = (_Float16)f; return x.s;
}
__device__ __forceinline__ void gload_lds16(const void* g, void* l) {
  __builtin_amdgcn_global_load_lds((const __attribute__((address_space(1))) unsigned int*)g,
                                   (__attribute__((address_space(3))) unsigned int*)l, 16, 0, 0);
}

// ============ merged input transform ============
__global__ void in_all(const float* __restrict__ in1, const float* __restrict__ in2,
                       unsigned short* __restrict__ o1, unsigned short* __restrict__ o2) {
  int i = blockIdx.x * 256 + threadIdx.x;
  const int p1 = 32 * 255 * 255;
  const int p2 = 32 * 127 * 127;
  const float* in;
  unsigned short* o;
  int HW;
  if (i < p1) {
    in = in1; o = o1; HW = 255 * 255;
  } else if (i < p1 + p2) {
    i -= p1; in = in2; o = o2; HW = 127 * 127;
  } else return;
  int n = i / HW;
  int r = i - n * HW;
  const float* p = in + (long)n * 3 * HW + r;
  uint2 v;
  v.x = (unsigned)f2h(p[0]) | ((unsigned)f2h(p[HW]) << 16);
  v.y = (unsigned)f2h(p[2 * HW]);
  ((uint2*)o)[i] = v;
}

// ============ merged weight transform ============
__device__ __forceinline__ void wtx(const float* __restrict__ w, unsigned short* __restrict__ o,
                                    long i, int Co, int Co_pad, int Ci, int KK) {
  int ci = (int)(i % Ci);
  long r = i / Ci;
  int co = (int)(r % Co_pad);
  int rk = (int)(r / Co_pad);
  float v = 0.f;
  if (co < Co) v = w[((long)co * Ci + ci) * KK + rk];
  o[i] = f2h(v);
}
__global__ void wt_all(const float* __restrict__ w1, const float* __restrict__ w2,
                       const float* __restrict__ w3, const float* __restrict__ w4,
                       const float* __restrict__ w5,
                       unsigned short* __restrict__ W1h, unsigned short* __restrict__ W2,
                       unsigned short* __restrict__ W3, unsigned short* __restrict__ W4,
                       unsigned short* __restrict__ W5) {
  long i = (long)blockIdx.x * 256 + threadIdx.x;
  const long t1 = 17 * 128 * 32;
  const long t2 = 256l * KPAD2;     // conv2: [Co][Kpad] layout
  const long t3 = 9l * 256 * 256;
  const long t4 = 9l * 256 * 192;
  const long t5 = 9l * 128 * 192;
  if (i < t1) {
    int j = (int)(i & 31);
    int r = (int)(i >> 5);
    int co = r & 127;
    int kk = r >> 7;
    int run = kk * 4 + (j >> 3);
    int ky = run / 6;
    int e = (run - ky * 6) * 8 + (j & 7);
    int kx = e >> 2, c = e & 3;
    float v = 0.f;
    if (ky < 11 && kx < 11 && c < 3 && co < 96)
      v = w1[((co * 3 + c) * 11 + ky) * 11 + kx];
    W1h[i] = f2h(v);
  } else if (i < t1 + t2) {
    long ii = i - t1;
    int co = (int)(ii / KPAD2);
    int k = (int)(ii - (long)co * KPAD2);
    int e = k / 96, ci = k - (k / 96) * 96;
    float v = 0.f;
    if (e < 25) v = w2[((long)co * 96 + ci) * 25 + e];
    W2[ii] = f2h(v);
  } else if (i < t1 + t2 + t3) {
    wtx(w3, W3, i - t1 - t2, 192, 256, 256, 9);
  } else if (i < t1 + t2 + t3 + t4) {
    wtx(w4, W4, i - t1 - t2 - t3, 192, 256, 192, 9);
  } else if (i < t1 + t2 + t3 + t4 + t5) {
    wtx(w5, W5, i - t1 - t2 - t3 - t4, 128, 128, 192, 9);
  }
}

// ============ conv1 MFMA (unchanged r11 structure) ============
__global__ __launch_bounds__(256)
void conv1_mfma(const unsigned short* __restrict__ in, const unsigned short* __restrict__ wt,
                unsigned short* __restrict__ out, float* __restrict__ part,
                int Hi1, int Ho1, int NPIX1, int BX1, long inOff2, long outOff2,
                int Hi2, int Ho2, int NPIX2) {
  __shared__ __align__(16) unsigned short sA[2][128 * 32];
  __shared__ __align__(16) unsigned short sB[2][128 * 32];
  __shared__ int sOB[128];
  __shared__ float sRed[4][64][2];
  const int t = threadIdx.x;
  const int bxg = blockIdx.x;
  const bool br2 = bxg >= BX1;
  const int lbx = br2 ? bxg - BX1 : bxg;
  const unsigned short* inB = in + (br2 ? inOff2 : 0);
  unsigned short* outB = out + (br2 ? outOff2 : 0);
  const int Hi = br2 ? Hi2 : Hi1, Wi = Hi;
  const int Ho = br2 ? Ho2 : Ho1, Wo = Ho;
  const int NPIX = br2 ? NPIX2 : NPIX1;
  const int px0 = lbx * 128;
  if (t < 128) {
    int g = px0 + t;
    int ob = -1;
    if (g < NPIX) {
      int n = g / (Ho * Wo);
      int r = g - n * Ho * Wo;
      int oy = r / Wo, ox = r - (r / Wo) * Wo;
      ob = ((n * Ho + oy) * Wo + ox) * 96;
    }
    sOB[t] = ob;
  }
  long rbase[2];
#pragma unroll
  for (int i = 0; i < 2; ++i) {
    int pxl = i * 64 + (t >> 2);
    int g = px0 + pxl;
    long rb = 0;
    if (g < NPIX) {
      int n = g / (Ho * Wo);
      int r = g - n * Ho * Wo;
      int oy = r / Wo, ox = r - (r / Wo) * Wo;
      rb = ((long)(n * Hi + 2 * oy) * Wi + 2 * ox) * 4;
    }
    rbase[i] = rb;
  }
  const int swz = (t & 3) ^ ((t >> 3) & 3);
  const int W4 = Wi * 4;
  f32x4 acc[4][4];
  f32x4 zz = {0.f, 0.f, 0.f, 0.f};
#pragma unroll
  for (int m = 0; m < 4; ++m)
#pragma unroll
    for (int n = 0; n < 4; ++n) acc[m][n] = zz;
  const int w = t >> 6;
  const int l = t & 63;
  const int wpx = (w & 1) * 64, wco = (w >> 1) * 64;
  const int arow = wpx + (l & 15);
  const int brow = wco + (l & 15);
  const int q8s = (((l >> 4) ^ (((l & 15) >> 1) & 3)) * 8);

  auto stage = [&](int buf, int kk) {
    int run = kk * 4 + swz;
    int ky = run / 6;
    int e0 = (run - ky * 6) * 8;
    long koff = (long)ky * W4 + e0;
    gload_lds16(inB + rbase[0] + koff, &sA[buf][t * 8]);
    gload_lds16(inB + rbase[1] + koff, &sA[buf][(256 + t) * 8]);
    const unsigned short* wp = wt + (long)kk * 4096;
    gload_lds16(wp + (t >> 2) * 32 + swz * 8, &sB[buf][t * 8]);
    gload_lds16(wp + 2048 + (t >> 2) * 32 + swz * 8, &sB[buf][(256 + t) * 8]);
  };

  stage(0, 0);
  __syncthreads();
  int cur = 0;
#pragma unroll 1
  for (int kk = 0; kk < 17; ++kk) {
    if (kk + 1 < 17) stage(cur ^ 1, kk + 1);
    f16x8 av[4], bv[4];
#pragma unroll
    for (int m = 0; m < 4; ++m) av[m] = *(const f16x8*)&sA[cur][(arow + m * 16) * 32 + q8s];
#pragma unroll
    for (int n = 0; n < 4; ++n) bv[n] = *(const f16x8*)&sB[cur][(brow + n * 16) * 32 + q8s];
#pragma unroll
    for (int m = 0; m < 4; ++m)
#pragma unroll
      for (int n = 0; n < 4; ++n)
        acc[m][n] = __builtin_amdgcn_mfma_f32_16x16x32_f16(av[m], bv[n], acc[m][n], 0, 0, 0);
    __syncthreads();
    cur ^= 1;
  }
#pragma unroll
  for (int m = 0; m < 4; ++m) {
#pragma unroll
    for (int r = 0; r < 4; ++r) {
      int pxl = wpx + m * 16 + (l >> 4) * 4 + r;
      int ob = sOB[pxl];
#pragma unroll
      for (int n = 0; n < 4; ++n) {
        int co = wco + n * 16 + (l & 15);
        if (ob >= 0 && co < 96) outB[ob + co] = f2h(acc[m][n][r]);
      }
    }
  }
  float sn[4], qn[4];
#pragma unroll
  for (int n = 0; n < 4; ++n) { sn[n] = 0.f; qn[n] = 0.f; }
#pragma unroll
  for (int m = 0; m < 4; ++m) {
#pragma unroll
    for (int r = 0; r < 4; ++r) {
      int pxl = wpx + m * 16 + (l >> 4) * 4 + r;
      float msk = (px0 + pxl < NPIX) ? 1.f : 0.f;
#pragma unroll
      for (int n = 0; n < 4; ++n) {
        float v = acc[m][n][r] * msk;
        sn[n] += v;
        qn[n] = fmaf(v, v, qn[n]);
      }
    }
  }
#pragma unroll
  for (int n = 0; n < 4; ++n) {
    sn[n] += __shfl_xor(sn[n], 16, 64);
    sn[n] += __shfl_xor(sn[n], 32, 64);
    qn[n] += __shfl_xor(qn[n], 16, 64);
    qn[n] += __shfl_xor(qn[n], 32, 64);
  }
  if (l < 16) {
#pragma unroll
    for (int n = 0; n < 4; ++n) {
      sRed[w][n * 16 + l][0] = sn[n];
      sRed[w][n * 16 + l][1] = qn[n];
    }
  }
  __syncthreads();
  if (t < 128) {
    int wb = (t >> 6) << 1;
    int cl = t & 63;
    float S = sRed[wb][cl][0] + sRed[wb + 1][cl][0];
    float Q = sRed[wb][cl][1] + sRed[wb + 1][cl][1];
    long idx = ((long)t * gridDim.x + bxg) * 2;
    part[idx] = S;
    part[idx + 1] = Q;
  }
}

// ============ conv2: 256x256 tile, BK=64, 8 waves, counted-vmcnt phase schedule ============
__global__ __launch_bounds__(512, 1)
void conv2_big(const unsigned short* __restrict__ in, const unsigned short* __restrict__ wt,
               unsigned short* __restrict__ out, float* __restrict__ part,
               int Hi1, int Ho1, int NPIX1, int BX1, long inOff2, long outOff2,
               int Hi2, int Ho2, int NPIX2) {
  __shared__ __align__(16) unsigned short sA[2][2][256 * 32];
  __shared__ __align__(16) unsigned short sB[2][2][256 * 32];
  __shared__ int sOB[256];
  __shared__ float sRed[8][64][2];
  const int t = threadIdx.x;
  const int bxg = blockIdx.x;
  const bool br2 = bxg >= BX1;
  const int lbx = br2 ? bxg - BX1 : bxg;
  const unsigned short* inB = in + (br2 ? inOff2 : 0);
  unsigned short* outB = out + (br2 ? outOff2 : 0);
  const int Hi = br2 ? Hi2 : Hi1, Wi = Hi;
  const int Ho = br2 ? Ho2 : Ho1, Wo = Ho;
  const int NPIX = br2 ? NPIX2 : NPIX1;
  const int px0 = lbx * 256;
  if (t < 256) {
    int g = px0 + t;
    int ob = -1;
    if (g < NPIX) {
      int n = g / (Ho * Wo);
      int r = g - n * Ho * Wo;
      int oy = r / Wo, ox = r - (r / Wo) * Wo;
      ob = ((n * Ho + oy) * Wo + ox) * 256;
    }
    sOB[t] = ob;
  }
  // A staging rows: (t>>2) and (t>>2)+128
  long rbase[2];
#pragma unroll
  for (int j = 0; j < 2; ++j) {
    int row = (t >> 2) + j * 128;
    int g = px0 + row;
    long rb = 0;
    if (g < NPIX) {
      int n = g / (Ho * Wo);
      int r = g - n * Ho * Wo;
      int oy = r / Wo, ox = r - (r / Wo) * Wo;
      rb = ((long)(n * Hi + oy) * Wi + ox) * 96;
    }
    rbase[j] = rb;
  }
  const int w = t >> 6;       // wave 0..7
  const int l = t & 63;
  const int wr = w >> 2;      // 0..1 -> px rows wr*128
  const int wc = w & 3;       // 0..3 -> co cols wc*64
  f32x4 acc[8][4];
  f32x4 zz = {0.f, 0.f, 0.f, 0.f};
#pragma unroll
  for (int m = 0; m < 8; ++m)
#pragma unroll
    for (int n = 0; n < 4; ++n) acc[m][n] = zz;

  const int kseg = (t & 3) * 8;          // k sub-offset within 32-K half
  const int bco = t >> 2;                // B staging co row base

  auto stage = [&](int tile, int half, int buf) {
    int k = tile * 64 + half * 32 + kseg;
    int e = k / 96;
    int ci = k - e * 96;
    int ky = e / 5, kx = e - ky * 5;
    long koff = (long)(ky * Wi + kx) * 96 + ci;
    unsigned short* dA = &sA[buf][half][t * 8];
    gload_lds16(inB + rbase[0] + koff, dA);
    gload_lds16(inB + rbase[1] + koff, dA + 4096);
    const unsigned short* ws = wt + (long)bco * KPAD2 + k;
    unsigned short* dB = &sB[buf][half][t * 8];
    gload_lds16(ws, dB);
    gload_lds16(ws + 128l * KPAD2, dB + 4096);
  };

  auto compute = [&](int buf, int half) {
    const unsigned short* A = &sA[buf][half][0];
    const unsigned short* B = &sB[buf][half][0];
    f16x8 av[8], bv[4];
#pragma unroll
    for (int m = 0; m < 8; ++m)
      av[m] = *(const f16x8*)&A[(wr * 128 + (l & 15) + m * 16) * 32 + (l >> 4) * 8];
#pragma unroll
    for (int n = 0; n < 4; ++n)
      bv[n] = *(const f16x8*)&B[(wc * 64 + (l & 15) + n * 16) * 32 + (l >> 4) * 8];
#pragma unroll
    for (int m = 0; m < 8; ++m)
#pragma unroll
      for (int n = 0; n < 4; ++n)
        acc[m][n] = __builtin_amdgcn_mfma_f32_16x16x32_f16(av[m], bv[n], acc[m][n], 0, 0, 0);
  };

  // prologue: tile0 (both halves) + tile1 half0
  stage(0, 0, 0);
  stage(0, 1, 0);
  stage(1, 0, 1);
  asm volatile("s_waitcnt vmcnt(4) lgkmcnt(0)" ::: "memory");
  __builtin_amdgcn_sched_barrier(0);
  __builtin_amdgcn_s_barrier();
  __builtin_amdgcn_sched_barrier(0);
#pragma unroll 1
  for (int tt = 0; tt < NT2; ++tt) {
    const int b = tt & 1;
    const int s1 = (tt + 1 < NT2) ? tt + 1 : NT2 - 1;
    const int s2 = (tt + 2 < NT2) ? tt + 2 : NT2 - 1;
    // P0: stage next tile's half1 (other buf); compute current half0
    stage(s1, 1, b ^ 1);
    compute(b, 0);
    asm volatile("s_waitcnt vmcnt(8)" ::: "memory");
    __builtin_amdgcn_sched_barrier(0);
    __builtin_amdgcn_s_barrier();
    __builtin_amdgcn_sched_barrier(0);
    // P1: stage tile+2's half0 into current buf's consumed half0; compute half1
    stage(s2, 0, b);
    compute(b, 1);
    asm volatile("s_waitcnt vmcnt(8)" ::: "memory");
    __builtin_amdgcn_sched_barrier(0);
    __builtin_amdgcn_s_barrier();
    __builtin_amdgcn_sched_barrier(0);
  }
  // epilogue: C-write
#pragma unroll
  for (int m = 0; m < 8; ++m) {
#pragma unroll
    for (int r = 0; r < 4; ++r) {
      int row = wr * 128 + m * 16 + (l >> 4) * 4 + r;
      int ob = sOB[row];
      if (ob >= 0) {
#pragma unroll
        for (int n = 0; n < 4; ++n) {
          int co = wc * 64 + n * 16 + (l & 15);
          outB[ob + co] = f2h(acc[m][n][r]);
        }
      }
    }
  }
  // fused BN-stat partials
  float sn[4], qn[4];
#pragma unroll
  for (int n = 0; n < 4; ++n) { sn[n] = 0.f; qn[n] = 0.f; }
#pragma unroll
  for (int m = 0; m < 8; ++m) {
#pragma unroll
    for (int r = 0; r < 4; ++r) {
      int row = wr * 128 + m * 16 + (l >> 4) * 4 + r;
      float msk = (px0 + row < NPIX) ? 1.f : 0.f;
#pragma unroll
      for (int n = 0; n < 4; ++n) {
        float v = acc[m][n][r] * msk;
        sn[n] += v;
        qn[n] = fmaf(v, v, qn[n]);
      }
    }
  }
#pragma unroll
  for (int n = 0; n < 4; ++n) {
    sn[n] += __shfl_xor(sn[n], 16, 64);
    sn[n] += __shfl_xor(sn[n], 32, 64);
    qn[n] += __shfl_xor(qn[n], 16, 64);
    qn[n] += __shfl_xor(qn[n], 32, 64);
  }
  if (l < 16) {
#pragma unroll
    for (int n = 0; n < 4; ++n) {
      sRed[w][n * 16 + l][0] = sn[n];
      sRed[w][n * 16 + l][1] = qn[n];
    }
  }
  __syncthreads();
  if (t < 256) {
    int wcg = t >> 6;
    int idx = t & 63;
    float S = sRed[wcg][idx][0] + sRed[wcg + 4][idx][0];
    float Q = sRed[wcg][idx][1] + sRed[wcg + 4][idx][1];
    long o = ((long)t * gridDim.x + bxg) * 2;
    part[o] = S;
    part[o + 1] = Q;
  }
}

// ============ implicit-GEMM MFMA conv (layers 3-5), r11 structure ============
template <int K>
__global__ __launch_bounds__(256)
void conv_mfma(const unsigned short* __restrict__ in, const unsigned short* __restrict__ wt,
               unsigned short* __restrict__ out, float* __restrict__ part,
               int Ci, int Co_pad, int Co_real,
               int Hi1, int Ho1, int NPIX1, int BX1, long inOff2, long outOff2,
               int Hi2, int Ho2, int NPIX2) {
  __shared__ __align__(16) unsigned short sA[2][128 * 32];
  __shared__ __align__(16) unsigned short sB[2][128 * 32];
  __shared__ int sOB[128];
  __shared__ float sRed[4][64][2];
  const int t = threadIdx.x;
  const int bxg = blockIdx.x;
  const bool br2 = bxg >= BX1;
  const int lbx = br2 ? bxg - BX1 : bxg;
  const unsigned short* inB = in + (br2 ? inOff2 : 0);
  unsigned short* outB = out + (br2 ? outOff2 : 0);
  const int Hi = br2 ? Hi2 : Hi1, Wi = Hi;
  const int Ho = br2 ? Ho2 : Ho1, Wo = Ho;
  const int NPIX = br2 ? NPIX2 : NPIX1;
  const int px0 = lbx * 128;
  const int co0 = blockIdx.y * 128;
  if (t < 128) {
    int g = px0 + t;
    int ob = -1;
    if (g < NPIX) {
      int n = g / (Ho * Wo);
      int r = g - n * Ho * Wo;
      int oy = r / Wo, ox = r - (r / Wo) * Wo;
      ob = ((n * Ho + oy) * Wo + ox) * Co_real;
    }
    sOB[t] = ob;
  }
  long rbase[2];
#pragma unroll
  for (int i = 0; i < 2; ++i) {
    int pxl = i * 64 + (t >> 2);
    int g = px0 + pxl;
    long rb = 0;
    if (g < NPIX) {
      int n = g / (Ho * Wo);
      int r = g - n * Ho * Wo;
      int oy = r / Wo, ox = r - (r / Wo) * Wo;
      rb = ((long)(n * Hi + oy) * Wi + ox) * Ci;
    }
    rbase[i] = rb;
  }
  const int seg8 = ((t & 3) ^ ((t >> 3) & 3)) * 8;
  const int colA = t >> 2;
  f32x4 acc[4][4];
  f32x4 zz = {0.f, 0.f, 0.f, 0.f};
#pragma unroll
  for (int m = 0; m < 4; ++m)
#pragma unroll
    for (int n = 0; n < 4; ++n) acc[m][n] = zz;
  const int w = t >> 6;
  const int l = t & 63;
  const int wpx = (w & 1) * 64, wco = (w >> 1) * 64;
  const int arow = wpx + (l & 15);
  const int brow = wco + (l & 15);
  const int q8s = (((l >> 4) ^ (((l & 15) >> 1) & 3)) * 8);
  int ci0 = 0, kx = 0, ky = 0;
  const int NK = (Ci >> 5) * K * K;

  auto stage = [&](int buf) {
    long koff = (long)(ky * Wi + kx) * Ci + ci0 + seg8;
    gload_lds16(inB + rbase[0] + koff, &sA[buf][t * 8]);
    gload_lds16(inB + rbase[1] + koff, &sA[buf][(256 + t) * 8]);
    long wbase = (long)((ky * K + kx) * Co_pad + co0) * Ci + ci0 + seg8;
    gload_lds16(wt + wbase + (long)colA * Ci, &sB[buf][t * 8]);
    gload_lds16(wt + wbase + (long)(64 + colA) * Ci, &sB[buf][(256 + t) * 8]);
    ci0 += 32;
    if (ci0 == Ci) { ci0 = 0; ++kx; if (kx == K) { kx = 0; ++ky; } }
  };

  stage(0);
  __syncthreads();
  int cur = 0;
#pragma unroll 1
  for (int kk = 0; kk < NK; ++kk) {
    if (kk + 1 < NK) stage(cur ^ 1);
    f16x8 av[4], bv[4];
#pragma unroll
    for (int m = 0; m < 4; ++m) av[m] = *(const f16x8*)&sA[cur][(arow + m * 16) * 32 + q8s];
#pragma unroll
    for (int n = 0; n < 4; ++n) bv[n] = *(const f16x8*)&sB[cur][(brow + n * 16) * 32 + q8s];
#pragma unroll
    for (int m = 0; m < 4; ++m)
#pragma unroll
      for (int n = 0; n < 4; ++n)
        acc[m][n] = __builtin_amdgcn_mfma_f32_16x16x32_f16(av[m], bv[n], acc[m][n], 0, 0, 0);
    __syncthreads();
    cur ^= 1;
  }
#pragma unroll
  for (int m = 0; m < 4; ++m) {
#pragma unroll
    for (int r = 0; r < 4; ++r) {
      int pxl = wpx + m * 16 + (l >> 4) * 4 + r;
      int ob = sOB[pxl];
#pragma unroll
      for (int n = 0; n < 4; ++n) {
        int co = co0 + wco + n * 16 + (l & 15);
        if (ob >= 0 && co < Co_real) outB[ob + co] = f2h(acc[m][n][r]);
      }
    }
  }
  float sn[4], qn[4];
#pragma unroll
  for (int n = 0; n < 4; ++n) { sn[n] = 0.f; qn[n] = 0.f; }
#pragma unroll
  for (int m = 0; m < 4; ++m) {
#pragma unroll
    for (int r = 0; r < 4; ++r) {
      int pxl = wpx + m * 16 + (l >> 4) * 4 + r;
      float msk = (px0 + pxl < NPIX) ? 1.f : 0.f;
#pragma unroll
      for (int n = 0; n < 4; ++n) {
        float v = acc[m][n][r] * msk;
        sn[n] += v;
        qn[n] = fmaf(v, v, qn[n]);
      }
    }
  }
#pragma unroll
  for (int n = 0; n < 4; ++n) {
    sn[n] += __shfl_xor(sn[n], 16, 64);
    sn[n] += __shfl_xor(sn[n], 32, 64);
    qn[n] += __shfl_xor(qn[n], 16, 64);
    qn[n] += __shfl_xor(qn[n], 32, 64);
  }
  if (l < 16) {
#pragma unroll
    for (int n = 0; n < 4; ++n) {
      sRed[w][n * 16 + l][0] = sn[n];
      sRed[w][n * 16 + l][1] = qn[n];
    }
  }
  __syncthreads();
  if (t < 128) {
    int wb = (t >> 6) << 1;
    int cl = t & 63;
    float S = sRed[wb][cl][0] + sRed[wb + 1][cl][0];
    float Q = sRed[wb][cl][1] + sRed[wb + 1][cl][1];
    long idx = ((long)(co0 + t) * gridDim.x + bxg) * 2;
    part[idx] = S;
    part[idx + 1] = Q;
  }
}

// ============ BN finalize, branch-merged ============
__global__ void bn_finalize(const float* __restrict__ part, const float* __restrict__ g,
                            const float* __restrict__ b, float* __restrict__ sc,
                            float* __restrict__ sh, int C, int BX1, int BXtot,
                            float cnt1, float cnt2) {
  const int cb = blockIdx.x;
  const bool br2 = cb >= C;
  const int c = br2 ? cb - C : cb;
  const int k0 = br2 ? BX1 : 0;
  const int k1 = br2 ? BXtot : BX1;
  const float cnt = br2 ? cnt2 : cnt1;
  const int t = threadIdx.x;
  float s = 0.f, q = 0.f;
  const float* pc = part + (long)c * BXtot * 2;
  for (int k = k0 + t; k < k1; k += 256) {
    s += pc[k * 2];
    q += pc[k * 2 + 1];
  }
  __shared__ float ss[256], qq[256];
  ss[t] = s; qq[t] = q;
  __syncthreads();
  for (int off = 128; off > 0; off >>= 1) {
    if (t < off) { ss[t] += ss[t + off]; qq[t] += qq[t + off]; }
    __syncthreads();
  }
  if (t == 0) {
    float m = ss[0] / cnt;
    float v = qq[0] / cnt - m * m;
    float r = rsqrtf(v + 1e-5f);
    float scl = r * g[c];
    int o = c + (br2 ? 256 : 0);
    sc[o] = scl;
    sh[o] = b[c] - m * scl;
  }
}

// ============ BN apply, branch-merged ============
template <bool RELU, bool OUTF32>
__global__ void bn_apply_k(const unsigned short* __restrict__ x, void* __restrict__ y,
                           const float* __restrict__ sc, const float* __restrict__ sh,
                           int C, long t81, long t82, long xOff2, long yOff2q4) {
  long i = (long)blockIdx.x * blockDim.x + threadIdx.x;
  if (i >= t81 + t82) return;
  const bool br2 = i >= t81;
  const long ii = br2 ? i - t81 : i;
  const int scO = br2 ? 256 : 0;
  const uint4 v = ((const uint4*)x + (br2 ? xOff2 : 0))[ii];
  int c0 = (int)((ii * 8) % C);
  const float4 s0 = *(const float4*)&sc[scO + c0];
  const float4 s1 = *(const float4*)&sc[scO + c0 + 4];
  const float4 h0 = *(const float4*)&sh[scO + c0];
  const float4 h1 = *(const float4*)&sh[scO + c0 + 4];
  float f[8];
  f[0] = h2f((unsigned short)(v.x & 0xffff)); f[1] = h2f((unsigned short)(v.x >> 16));
  f[2] = h2f((unsigned short)(v.y & 0xffff)); f[3] = h2f((unsigned short)(v.y >> 16));
  f[4] = h2f((unsigned short)(v.z & 0xffff)); f[5] = h2f((unsigned short)(v.z >> 16));
  f[6] = h2f((unsigned short)(v.w & 0xffff)); f[7] = h2f((unsigned short)(v.w >> 16));
  const float S[8] = {s0.x, s0.y, s0.z, s0.w, s1.x, s1.y, s1.z, s1.w};
  const float H[8] = {h0.x, h0.y, h0.z, h0.w, h1.x, h1.y, h1.z, h1.w};
#pragma unroll
  for (int j = 0; j < 8; ++j) {
    f[j] = fmaf(f[j], S[j], H[j]);
    if (RELU) f[j] = fmaxf(f[j], 0.f);
  }
  if (OUTF32) {
    float4* yb = (float4*)y + (br2 ? yOff2q4 : 0);
    float4 o0 = {f[0], f[1], f[2], f[3]}, o1 = {f[4], f[5], f[6], f[7]};
    yb[2 * ii] = o0;
    yb[2 * ii + 1] = o1;
  } else {
    uint4 o;
    o.x = (unsigned)f2h(f[0]) | ((unsigned)f2h(f[1]) << 16);
    o.y = (unsigned)f2h(f[2]) | ((unsigned)f2h(f[3]) << 16);
    o.z = (unsigned)f2h(f[4]) | ((unsigned)f2h(f[5]) << 16);
    o.w = (unsigned)f2h(f[6]) | ((unsigned)f2h(f[7]) << 16);
    ((uint4*)y + (br2 ? xOff2 : 0))[ii] = o;
  }
}

// ============ fused BN+ReLU+MaxPool 3x3 s2, branch-merged ============
__global__ void bn_pool_k(const unsigned short* __restrict__ in, unsigned short* __restrict__ out,
                          const float* __restrict__ sc, const float* __restrict__ sh,
                          int C8, int Hi1, int Ho1, long t81, long inOff2, long outOff2,
                          int Hi2, int Ho2, long t82) {
  long i = (long)blockIdx.x * blockDim.x + threadIdx.x;
  if (i >= t81 + t82) return;
  const bool br2 = i >= t81;
  const long ii = br2 ? i - t81 : i;
  const int Hi = br2 ? Hi2 : Hi1, Wi = Hi;
  const int Ho = br2 ? Ho2 : Ho1, Wo = Ho;
  const int scO = br2 ? 256 : 0;
  const uint4* inB = (const uint4*)in + (br2 ? inOff2 : 0);
  uint4* outB = (uint4*)out + (br2 ? outOff2 : 0);
  int cg = (int)(ii % C8);
  long r = ii / C8;
  int ox = (int)(r % Wo);
  r /= Wo;
  int oy = (int)(r % Ho);
  int n = (int)(r / Ho);
  const int c0 = cg * 8;
  const float4 s0 = *(const float4*)&sc[scO + c0];
  const float4 s1 = *(const float4*)&sc[scO + c0 + 4];
  const float4 h0 = *(const float4*)&sh[scO + c0];
  const float4 h1 = *(const float4*)&sh[scO + c0 + 4];
  const float S[8] = {s0.x, s0.y, s0.z, s0.w, s1.x, s1.y, s1.z, s1.w};
  const float H[8] = {h0.x, h0.y, h0.z, h0.w, h1.x, h1.y, h1.z, h1.w};
  const uint4* bp = inB + ((long)(n * Hi + 2 * oy) * Wi + 2 * ox) * C8 + cg;
  float m[8];
#pragma unroll
  for (int j = 0; j < 8; ++j) m[j] = -3.4e38f;
#pragma unroll
  for (int dy = 0; dy < 3; ++dy)
#pragma unroll
    for (int dx = 0; dx < 3; ++dx) {
      const uint4 v = bp[((long)dy * Wi + dx) * C8];
      float f[8];
      f[0] = h2f((unsigned short)(v.x & 0xffff)); f[1] = h2f((unsigned short)(v.x >> 16));
      f[2] = h2f((unsigned short)(v.y & 0xffff)); f[3] = h2f((unsigned short)(v.y >> 16));
      f[4] = h2f((unsigned short)(v.z & 0xffff)); f[5] = h2f((unsigned short)(v.z >> 16));
      f[6] = h2f((unsigned short)(v.w & 0xffff)); f[7] = h2f((unsigned short)(v.w >> 16));
#pragma unroll
      for (int j = 0; j < 8; ++j) {
        f[j] = fmaxf(fmaf(f[j], S[j], H[j]), 0.f);
        m[j] = fmaxf(m[j], f[j]);
      }
    }
  uint4 o;
  o.x = (unsigned)f2h(m[0]) | ((unsigned)f2h(m[1]) << 16);
  o.y = (unsigned)f2h(m[2]) | ((unsigned)f2h(m[3]) << 16);
  o.z = (unsigned)f2h(m[4]) | ((unsigned)f2h(m[5]) << 16);
  o.w = (unsigned)f2h(m[6]) | ((unsigned)f2h(m[7]) << 16);
  outB[ii] = o;
}

// ============ cross-correlation ============
__global__ void xcorr_part(const float* __restrict__ o1, const float* __restrict__ o2,
                           float* __restrict__ part) {
  const int p = blockIdx.x;
  const int b = blockIdx.y;
  const int oy = p / 17, ox = p - (p / 17) * 17;
  const float* o1b = o1 + (long)b * 22 * 22 * 128;
  const float* o2b = o2 + (long)b * 4608;
  float acc = 0.f;
  for (int i = threadIdx.x; i < 4608; i += 256) {
    int c = i & 127;
    int r = i >> 7;
    int kx = r % 6, ky = r / 6;
    acc = fmaf(o1b[((oy + ky) * 22 + ox + kx) * 128 + c], o2b[i], acc);
  }
#pragma unroll
  for (int off = 32; off > 0; off >>= 1) acc += __shfl_down(acc, off, 64);
  __shared__ float sh[4];
  const int lane = threadIdx.x & 63, wid = threadIdx.x >> 6;
  if (lane == 0) sh[wid] = acc;
  __syncthreads();
  if (threadIdx.x == 0) part[p * 32 + b] = sh[0] + sh[1] + sh[2] + sh[3];
}

__global__ void xcorr_out(const float* __restrict__ part, float* __restrict__ out, int total) {
  int i = blockIdx.x * 256 + threadIdx.x;
  if (i >= total) return;
  int p = i % 289;
  float s = 0.f;
  for (int b = 0; b < 32; ++b) s += part[p * 32 + b];
  out[i] = s * (1.f / 147456.f);
}

// ============ host ============
extern "C" void kernel_launch(void* const* d_in, const int* in_sizes, int n_in,
                              void* d_out, int out_size, void* d_ws, size_t ws_size,
                              hipStream_t stream) {
  (void)in_sizes; (void)n_in; (void)ws_size; (void)out_size;
  const float* input1 = (const float*)d_in[0];
  const float* input2 = (const float*)d_in[1];
  const float* cw[5];
  const float* bg[5];
  const float* bb[5];
  for (int i = 0; i < 5; ++i) {
    cw[i] = (const float*)d_in[2 + 2 * i];
    bg[i] = (const float*)d_in[12 + 2 * i];
    bb[i] = (const float*)d_in[13 + 2 * i];
  }
  const int H1a = 123, P1a = 61, H2a = 57, P2a = 28, H3a = 26, H4a = 24, H5a = 22;
  const int H1b = 59, P1b = 29, H2b = 25, P2b = 12, H3b = 10, H4b = 8, H5b = 6;
  auto NP = [](int h) { return 32 * h * h; };
  const int NP1a = NP(H1a), NP1b = NP(H1b);
  const int NP2a = NP(H2a), NP2b = NP(H2b);
  const int NP3a = NP(H3a), NP3b = NP(H3b);
  const int NP4a = NP(H4a), NP4b = NP(H4b);
  const int NP5a = NP(H5a), NP5b = NP(H5b);
  auto BX = [](int np) { return (np + 127) / 128; };

  char* p = (char*)d_ws;
  auto alloc = [&](size_t bytes) {
    char* r = p;
    p += (bytes + 255) & ~(size_t)255;
    return r;
  };
  unsigned short* P = (unsigned short*)alloc(((size_t)NP1a + NP1b) * 96 * 2);
  unsigned short* R = (unsigned short*)alloc(((size_t)NP(P1a) + NP(P1b)) * 96 * 2 + 262144);
  unsigned short* Q = (unsigned short*)alloc(((size_t)NP4a + NP4b) * 192 * 2);
  float* O12 = (float*)alloc(((size_t)NP5a + NP5b) * 128 * 4);
  unsigned short* I12h = (unsigned short*)alloc(((size_t)32 * 255 * 255 * 4 + (size_t)32 * 127 * 127 * 4) * 2 + 65536);
  unsigned short* W1h = (unsigned short*)alloc(17l * 128 * 32 * 2);
  unsigned short* W2 = (unsigned short*)alloc(256l * KPAD2 * 2);
  unsigned short* W3 = (unsigned short*)alloc(9l * 256 * 256 * 2);
  unsigned short* W4 = (unsigned short*)alloc(9l * 256 * 192 * 2);
  unsigned short* W5 = (unsigned short*)alloc(9l * 128 * 192 * 2);
  float* part = (float*)alloc(9000000);
  float* sc = (float*)alloc(512 * 4);
  float* sh = (float*)alloc(512 * 4);
  float* O1 = O12;
  float* O2 = O12 + (size_t)NP5a * 128;

  // merged transforms
  {
    long wt_tot = 17l * 128 * 32 + 256l * KPAD2 + 9l * 256 * 256 + 9l * 256 * 192 + 9l * 128 * 192;
    wt_all<<<(unsigned)((wt_tot + 255) / 256), 256, 0, stream>>>(cw[0], cw[1], cw[2], cw[3], cw[4],
                                                                 W1h, W2, W3, W4, W5);
    long in_tot = 32l * 255 * 255 + 32l * 127 * 127;
    in_all<<<(unsigned)((in_tot + 255) / 256), 256, 0, stream>>>(input1, input2, I12h,
                                                                 I12h + 32l * 255 * 255 * 4);
  }

  // ---- layer 1 ----
  {
    int BX1 = BX(NP1a), BXt = BX1 + BX(NP1b);
    conv1_mfma<<<(unsigned)BXt, 256, 0, stream>>>(I12h, W1h, P, part,
        255, H1a, NP1a, BX1, 32l * 255 * 255 * 4, (long)NP1a * 96,
        127, H1b, NP1b);
    bn_finalize<<<192, 256, 0, stream>>>(part, bg[0], bb[0], sc, sh, 96, BX1, BXt,
                                         (float)NP1a, (float)NP1b);
    long t81 = (long)NP(P1a) * 96 / 8, t82 = (long)NP(P1b) * 96 / 8;
    bn_pool_k<<<(unsigned)((t81 + t82 + 255) / 256), 256, 0, stream>>>(
        P, R, sc, sh, 12, H1a, P1a, t81, (long)NP1a * 96 / 8, t81, H1b, P1b, t82);
  }
  // ---- layer 2 (256x256 8-wave schedule) ----
  {
    int BX1 = (NP2a + 255) / 256, BXt = BX1 + (NP2b + 255) / 256;
    conv2_big<<<(unsigned)BXt, 512, 0, stream>>>(R, W2, P, part,
        P1a, H2a, NP2a, BX1, (long)NP(P1a) * 96, (long)NP2a * 256,
        P1b, H2b, NP2b);
    bn_finalize<<<512, 256, 0, stream>>>(part, bg[1], bb[1], sc, sh, 256, BX1, BXt,
                                         (float)NP2a, (float)NP2b);
    long t81 = (long)NP(P2a) * 256 / 8, t82 = (long)NP(P2b) * 256 / 8;
    bn_pool_k<<<(unsigned)((t81 + t82 + 255) / 256), 256, 0, stream>>>(
        P, R, sc, sh, 32, H2a, P2a, t81, (long)NP2a * 256 / 8, t81, H2b, P2b, t82);
  }
  // ---- layer 3 ----
  {
    int BX1 = BX(NP3a), BXt = BX1 + BX(NP3b);
    dim3 g((unsigned)BXt, 2);
    conv_mfma<3><<<g, 256, 0, stream>>>(R, W3, P, part, 256, 256, 192,
        P2a, H3a, NP3a, BX1, (long)NP(P2a) * 256, (long)NP3a * 192,
        P2b, H3b, NP3b);
    bn_finalize<<<384, 256, 0, stream>>>(part, bg[2], bb[2], sc, sh, 192, BX1, BXt,
                                         (float)NP3a, (float)NP3b);
    long t81 = (long)NP3a * 192 / 8, t82 = (long)NP3b * 192 / 8;
    bn_apply_k<true, false><<<(unsigned)((t81 + t82 + 255) / 256), 256, 0, stream>>>(
        P, P, sc, sh, 192, t81, t82, t81, 0);
  }
  // ---- layer 4 ----
  {
    int BX1 = BX(NP4a), BXt = BX1 + BX(NP4b);
    dim3 g((unsigned)BXt, 2);
    conv_mfma<3><<<g, 256, 0, stream>>>(P, W4, Q, part, 192, 256, 192,
        H3a, H4a, NP4a, BX1, (long)NP3a * 192, (long)NP4a * 192,
        H3b, H4b, NP4b);
    bn_finalize<<<384, 256, 0, stream>>>(part, bg[3], bb[3], sc, sh, 192, BX1, BXt,
                                         (float)NP4a, (float)NP4b);
    long t81 = (long)NP4a * 192 / 8, t82 = (long)NP4b * 192 / 8;
    bn_apply_k<true, false><<<(unsigned)((t81 + t82 + 255) / 256), 256, 0, stream>>>(
        Q, Q, sc, sh, 192, t81, t82, t81, 0);
  }
  // ---- layer 5 ----
  {
    int BX1 = BX(NP5a), BXt = BX1 + BX(NP5b);
    dim3 g((unsigned)BXt, 1);
    conv_mfma<3><<<g, 256, 0, stream>>>(Q, W5, P, part, 192, 128, 128,
        H4a, H5a, NP5a, BX1, (long)NP4a * 192, (long)NP5a * 128,
        H4b, H5b, NP5b);
    bn_finalize<<<256, 256, 0, stream>>>(part, bg[4], bb[4], sc, sh, 128, BX1, BXt,
                                         (float)NP5a, (float)NP5b);
    long t81 = (long)NP5a * 128 / 8, t82 = (long)NP5b * 128 / 8;
    bn_apply_k<false, true><<<(unsigned)((t81 + t82 + 255) / 256), 256, 0, stream>>>(
        P, O12, sc, sh, 128, t81, t82, t81, (long)NP5a * 128 / 4);
  }

  xcorr_part<<<dim3(289, 32), 256, 0, stream>>>(O1, O2, part);
  xcorr_out<<<(9248 + 255) / 256, 256, 0, stream>>>(part, (float*)d_out, 9248);
}

// Round 13
// 616.369 us; speedup vs baseline: 1.0057x; 1.0057x over previous
//
#include <hip/hip_runtime.h>
#include <hip/hip_bf16.h>
#include <cstdint>
#include <cstddef>

typedef __attribute__((ext_vector_type(8))) _Float16 f16x8;
typedef __attribute__((ext_vector_type(4))) float f32x4;

#define KPAD2 2432
#define NT2 38

__device__ __forceinline__ float h2f(unsigned short u) {
  union { unsigned short s; _Float16 h; } x; x.s = u; return (float)x.h;
}
__device__ __forceinline__ unsigned short f2h(float f) {
  union { unsigned short s; _Float16 h; } x; x.h = (_Float16)f; return x.s;
}
__device__ __forceinline__ void gload_lds16(const void* g, void* l) {
  __builtin_amdgcn_global_load_lds((const __attribute__((address_space(1))) unsigned int*)g,
                                   (__attribute__((address_space(3))) unsigned int*)l, 16, 0, 0);
}

// ============ merged input transform ============
__global__ void in_all(const float* __restrict__ in1, const float* __restrict__ in2,
                       unsigned short* __restrict__ o1, unsigned short* __restrict__ o2) {
  int i = blockIdx.x * 256 + threadIdx.x;
  const int p1 = 32 * 255 * 255;
  const int p2 = 32 * 127 * 127;
  const float* in;
  unsigned short* o;
  int HW;
  if (i < p1) {
    in = in1; o = o1; HW = 255 * 255;
  } else if (i < p1 + p2) {
    i -= p1; in = in2; o = o2; HW = 127 * 127;
  } else return;
  int n = i / HW;
  int r = i - n * HW;
  const float* p = in + (long)n * 3 * HW + r;
  uint2 v;
  v.x = (unsigned)f2h(p[0]) | ((unsigned)f2h(p[HW]) << 16);
  v.y = (unsigned)f2h(p[2 * HW]);
  ((uint2*)o)[i] = v;
}

// ============ merged weight transform ============
__device__ __forceinline__ void wtx(const float* __restrict__ w, unsigned short* __restrict__ o,
                                    long i, int Co, int Co_pad, int Ci, int KK) {
  int ci = (int)(i % Ci);
  long r = i / Ci;
  int co = (int)(r % Co_pad);
  int rk = (int)(r / Co_pad);
  float v = 0.f;
  if (co < Co) v = w[((long)co * Ci + ci) * KK + rk];
  o[i] = f2h(v);
}
__global__ void wt_all(const float* __restrict__ w1, const float* __restrict__ w2,
                       const float* __restrict__ w3, const float* __restrict__ w4,
                       const float* __restrict__ w5,
                       unsigned short* __restrict__ W1h, unsigned short* __restrict__ W2,
                       unsigned short* __restrict__ W3, unsigned short* __restrict__ W4,
                       unsigned short* __restrict__ W5) {
  long i = (long)blockIdx.x * 256 + threadIdx.x;
  const long t1 = 17 * 128 * 32;
  const long t2 = 256l * KPAD2;     // conv2: [Co][Kpad] layout
  const long t3 = 9l * 256 * 256;
  const long t4 = 9l * 256 * 192;
  const long t5 = 9l * 128 * 192;
  if (i < t1) {
    int j = (int)(i & 31);
    int r = (int)(i >> 5);
    int co = r & 127;
    int kk = r >> 7;
    int run = kk * 4 + (j >> 3);
    int ky = run / 6;
    int e = (run - ky * 6) * 8 + (j & 7);
    int kx = e >> 2, c = e & 3;
    float v = 0.f;
    if (ky < 11 && kx < 11 && c < 3 && co < 96)
      v = w1[((co * 3 + c) * 11 + ky) * 11 + kx];
    W1h[i] = f2h(v);
  } else if (i < t1 + t2) {
    long ii = i - t1;
    int co = (int)(ii / KPAD2);
    int k = (int)(ii - (long)co * KPAD2);
    int e = k / 96, ci = k - (k / 96) * 96;
    float v = 0.f;
    if (e < 25) v = w2[((long)co * 96 + ci) * 25 + e];
    W2[ii] = f2h(v);
  } else if (i < t1 + t2 + t3) {
    wtx(w3, W3, i - t1 - t2, 192, 256, 256, 9);
  } else if (i < t1 + t2 + t3 + t4) {
    wtx(w4, W4, i - t1 - t2 - t3, 192, 256, 192, 9);
  } else if (i < t1 + t2 + t3 + t4 + t5) {
    wtx(w5, W5, i - t1 - t2 - t3 - t4, 128, 128, 192, 9);
  }
}

// ============ conv1 MFMA (r11 structure) ============
__global__ __launch_bounds__(256)
void conv1_mfma(const unsigned short* __restrict__ in, const unsigned short* __restrict__ wt,
                unsigned short* __restrict__ out, float* __restrict__ part,
                int Hi1, int Ho1, int NPIX1, int BX1, long inOff2, long outOff2,
                int Hi2, int Ho2, int NPIX2) {
  __shared__ __align__(16) unsigned short sA[2][128 * 32];
  __shared__ __align__(16) unsigned short sB[2][128 * 32];
  __shared__ int sOB[128];
  __shared__ float sRed[4][64][2];
  const int t = threadIdx.x;
  const int bxg = blockIdx.x;
  const bool br2 = bxg >= BX1;
  const int lbx = br2 ? bxg - BX1 : bxg;
  const unsigned short* inB = in + (br2 ? inOff2 : 0);
  unsigned short* outB = out + (br2 ? outOff2 : 0);
  const int Hi = br2 ? Hi2 : Hi1, Wi = Hi;
  const int Ho = br2 ? Ho2 : Ho1, Wo = Ho;
  const int NPIX = br2 ? NPIX2 : NPIX1;
  const int px0 = lbx * 128;
  if (t < 128) {
    int g = px0 + t;
    int ob = -1;
    if (g < NPIX) {
      int n = g / (Ho * Wo);
      int r = g - n * Ho * Wo;
      int oy = r / Wo, ox = r - (r / Wo) * Wo;
      ob = ((n * Ho + oy) * Wo + ox) * 96;
    }
    sOB[t] = ob;
  }
  long rbase[2];
#pragma unroll
  for (int i = 0; i < 2; ++i) {
    int pxl = i * 64 + (t >> 2);
    int g = px0 + pxl;
    long rb = 0;
    if (g < NPIX) {
      int n = g / (Ho * Wo);
      int r = g - n * Ho * Wo;
      int oy = r / Wo, ox = r - (r / Wo) * Wo;
      rb = ((long)(n * Hi + 2 * oy) * Wi + 2 * ox) * 4;
    }
    rbase[i] = rb;
  }
  const int swz = (t & 3) ^ ((t >> 3) & 3);
  const int W4 = Wi * 4;
  f32x4 acc[4][4];
  f32x4 zz = {0.f, 0.f, 0.f, 0.f};
#pragma unroll
  for (int m = 0; m < 4; ++m)
#pragma unroll
    for (int n = 0; n < 4; ++n) acc[m][n] = zz;
  const int w = t >> 6;
  const int l = t & 63;
  const int wpx = (w & 1) * 64, wco = (w >> 1) * 64;
  const int arow = wpx + (l & 15);
  const int brow = wco + (l & 15);
  const int q8s = (((l >> 4) ^ (((l & 15) >> 1) & 3)) * 8);

  auto stage = [&](int buf, int kk) {
    int run = kk * 4 + swz;
    int ky = run / 6;
    int e0 = (run - ky * 6) * 8;
    long koff = (long)ky * W4 + e0;
    gload_lds16(inB + rbase[0] + koff, &sA[buf][t * 8]);
    gload_lds16(inB + rbase[1] + koff, &sA[buf][(256 + t) * 8]);
    const unsigned short* wp = wt + (long)kk * 4096;
    gload_lds16(wp + (t >> 2) * 32 + swz * 8, &sB[buf][t * 8]);
    gload_lds16(wp + 2048 + (t >> 2) * 32 + swz * 8, &sB[buf][(256 + t) * 8]);
  };

  stage(0, 0);
  __syncthreads();
  int cur = 0;
#pragma unroll 1
  for (int kk = 0; kk < 17; ++kk) {
    if (kk + 1 < 17) stage(cur ^ 1, kk + 1);
    f16x8 av[4], bv[4];
#pragma unroll
    for (int m = 0; m < 4; ++m) av[m] = *(const f16x8*)&sA[cur][(arow + m * 16) * 32 + q8s];
#pragma unroll
    for (int n = 0; n < 4; ++n) bv[n] = *(const f16x8*)&sB[cur][(brow + n * 16) * 32 + q8s];
#pragma unroll
    for (int m = 0; m < 4; ++m)
#pragma unroll
      for (int n = 0; n < 4; ++n)
        acc[m][n] = __builtin_amdgcn_mfma_f32_16x16x32_f16(av[m], bv[n], acc[m][n], 0, 0, 0);
    __syncthreads();
    cur ^= 1;
  }
#pragma unroll
  for (int m = 0; m < 4; ++m) {
#pragma unroll
    for (int r = 0; r < 4; ++r) {
      int pxl = wpx + m * 16 + (l >> 4) * 4 + r;
      int ob = sOB[pxl];
#pragma unroll
      for (int n = 0; n < 4; ++n) {
        int co = wco + n * 16 + (l & 15);
        if (ob >= 0 && co < 96) outB[ob + co] = f2h(acc[m][n][r]);
      }
    }
  }
  float sn[4], qn[4];
#pragma unroll
  for (int n = 0; n < 4; ++n) { sn[n] = 0.f; qn[n] = 0.f; }
#pragma unroll
  for (int m = 0; m < 4; ++m) {
#pragma unroll
    for (int r = 0; r < 4; ++r) {
      int pxl = wpx + m * 16 + (l >> 4) * 4 + r;
      float msk = (px0 + pxl < NPIX) ? 1.f : 0.f;
#pragma unroll
      for (int n = 0; n < 4; ++n) {
        float v = acc[m][n][r] * msk;
        sn[n] += v;
        qn[n] = fmaf(v, v, qn[n]);
      }
    }
  }
#pragma unroll
  for (int n = 0; n < 4; ++n) {
    sn[n] += __shfl_xor(sn[n], 16, 64);
    sn[n] += __shfl_xor(sn[n], 32, 64);
    qn[n] += __shfl_xor(qn[n], 16, 64);
    qn[n] += __shfl_xor(qn[n], 32, 64);
  }
  if (l < 16) {
#pragma unroll
    for (int n = 0; n < 4; ++n) {
      sRed[w][n * 16 + l][0] = sn[n];
      sRed[w][n * 16 + l][1] = qn[n];
    }
  }
  __syncthreads();
  if (t < 128) {
    int wb = (t >> 6) << 1;
    int cl = t & 63;
    float S = sRed[wb][cl][0] + sRed[wb + 1][cl][0];
    float Q = sRed[wb][cl][1] + sRed[wb + 1][cl][1];
    long idx = ((long)t * gridDim.x + bxg) * 2;
    part[idx] = S;
    part[idx + 1] = Q;
  }
}

// ============ conv2: 256x256 tile, BK=64, 8 waves, counted-vmcnt + bank swizzle ============
__global__ __launch_bounds__(512, 1)
void conv2_big(const unsigned short* __restrict__ in, const unsigned short* __restrict__ wt,
               unsigned short* __restrict__ out, float* __restrict__ part,
               int Hi1, int Ho1, int NPIX1, int BX1, long inOff2, long outOff2,
               int Hi2, int Ho2, int NPIX2) {
  __shared__ __align__(16) unsigned short sA[2][2][256 * 32];
  __shared__ __align__(16) unsigned short sB[2][2][256 * 32];
  __shared__ int sOB[256];
  __shared__ float sRed[8][64][2];
  const int t = threadIdx.x;
  const int bxg = blockIdx.x;
  const bool br2 = bxg >= BX1;
  const int lbx = br2 ? bxg - BX1 : bxg;
  const unsigned short* inB = in + (br2 ? inOff2 : 0);
  unsigned short* outB = out + (br2 ? outOff2 : 0);
  const int Hi = br2 ? Hi2 : Hi1, Wi = Hi;
  const int Ho = br2 ? Ho2 : Ho1, Wo = Ho;
  const int NPIX = br2 ? NPIX2 : NPIX1;
  const int px0 = lbx * 256;
  if (t < 256) {
    int g = px0 + t;
    int ob = -1;
    if (g < NPIX) {
      int n = g / (Ho * Wo);
      int r = g - n * Ho * Wo;
      int oy = r / Wo, ox = r - (r / Wo) * Wo;
      ob = ((n * Ho + oy) * Wo + ox) * 256;
    }
    sOB[t] = ob;
  }
  long rbase[2];
#pragma unroll
  for (int j = 0; j < 2; ++j) {
    int row = (t >> 2) + j * 128;
    int g = px0 + row;
    long rb = 0;
    if (g < NPIX) {
      int n = g / (Ho * Wo);
      int r = g - n * Ho * Wo;
      int oy = r / Wo, ox = r - (r / Wo) * Wo;
      rb = ((long)(n * Hi + oy) * Wi + ox) * 96;
    }
    rbase[j] = rb;
  }
  const int w = t >> 6;
  const int l = t & 63;
  const int wr = w >> 2;
  const int wc = w & 3;
  f32x4 acc[8][4];
  f32x4 zz = {0.f, 0.f, 0.f, 0.f};
#pragma unroll
  for (int m = 0; m < 8; ++m)
#pragma unroll
    for (int n = 0; n < 4; ++n) acc[m][n] = zz;

  // bank-conflict swizzle: phys slot (t&3) at row (t>>2) holds logical seg (t&3)^((t>>3)&3)
  const int kseg = ((t & 3) ^ ((t >> 3) & 3)) * 8;
  const int bco = t >> 2;
  const int q8s = (((l >> 4) ^ (((l & 15) >> 1) & 3)) * 8);

  auto stage = [&](int tile, int half, int buf) {
    int k = tile * 64 + half * 32 + kseg;
    int e = k / 96;
    int ci = k - e * 96;
    int ky = e / 5, kx = e - ky * 5;
    long koff = (long)(ky * Wi + kx) * 96 + ci;
    unsigned short* dA = &sA[buf][half][t * 8];
    gload_lds16(inB + rbase[0] + koff, dA);
    gload_lds16(inB + rbase[1] + koff, dA + 4096);
    const unsigned short* ws = wt + (long)bco * KPAD2 + k;
    unsigned short* dB = &sB[buf][half][t * 8];
    gload_lds16(ws, dB);
    gload_lds16(ws + 128l * KPAD2, dB + 4096);
  };

  auto compute = [&](int buf, int half) {
    const unsigned short* A = &sA[buf][half][0];
    const unsigned short* B = &sB[buf][half][0];
    f16x8 av[8], bv[4];
#pragma unroll
    for (int m = 0; m < 8; ++m)
      av[m] = *(const f16x8*)&A[(wr * 128 + (l & 15) + m * 16) * 32 + q8s];
#pragma unroll
    for (int n = 0; n < 4; ++n)
      bv[n] = *(const f16x8*)&B[(wc * 64 + (l & 15) + n * 16) * 32 + q8s];
#pragma unroll
    for (int m = 0; m < 8; ++m)
#pragma unroll
      for (int n = 0; n < 4; ++n)
        acc[m][n] = __builtin_amdgcn_mfma_f32_16x16x32_f16(av[m], bv[n], acc[m][n], 0, 0, 0);
  };

  stage(0, 0, 0);
  stage(0, 1, 0);
  stage(1, 0, 1);
  asm volatile("s_waitcnt vmcnt(4) lgkmcnt(0)" ::: "memory");
  __builtin_amdgcn_sched_barrier(0);
  __builtin_amdgcn_s_barrier();
  __builtin_amdgcn_sched_barrier(0);
#pragma unroll 1
  for (int tt = 0; tt < NT2; ++tt) {
    const int b = tt & 1;
    const int s1 = (tt + 1 < NT2) ? tt + 1 : NT2 - 1;
    const int s2 = (tt + 2 < NT2) ? tt + 2 : NT2 - 1;
    stage(s1, 1, b ^ 1);
    compute(b, 0);
    asm volatile("s_waitcnt vmcnt(8)" ::: "memory");
    __builtin_amdgcn_sched_barrier(0);
    __builtin_amdgcn_s_barrier();
    __builtin_amdgcn_sched_barrier(0);
    stage(s2, 0, b);
    compute(b, 1);
    asm volatile("s_waitcnt vmcnt(8)" ::: "memory");
    __builtin_amdgcn_sched_barrier(0);
    __builtin_amdgcn_s_barrier();
    __builtin_amdgcn_sched_barrier(0);
  }
#pragma unroll
  for (int m = 0; m < 8; ++m) {
#pragma unroll
    for (int r = 0; r < 4; ++r) {
      int row = wr * 128 + m * 16 + (l >> 4) * 4 + r;
      int ob = sOB[row];
      if (ob >= 0) {
#pragma unroll
        for (int n = 0; n < 4; ++n) {
          int co = wc * 64 + n * 16 + (l & 15);
          outB[ob + co] = f2h(acc[m][n][r]);
        }
      }
    }
  }
  float sn[4], qn[4];
#pragma unroll
  for (int n = 0; n < 4; ++n) { sn[n] = 0.f; qn[n] = 0.f; }
#pragma unroll
  for (int m = 0; m < 8; ++m) {
#pragma unroll
    for (int r = 0; r < 4; ++r) {
      int row = wr * 128 + m * 16 + (l >> 4) * 4 + r;
      float msk = (px0 + row < NPIX) ? 1.f : 0.f;
#pragma unroll
      for (int n = 0; n < 4; ++n) {
        float v = acc[m][n][r] * msk;
        sn[n] += v;
        qn[n] = fmaf(v, v, qn[n]);
      }
    }
  }
#pragma unroll
  for (int n = 0; n < 4; ++n) {
    sn[n] += __shfl_xor(sn[n], 16, 64);
    sn[n] += __shfl_xor(sn[n], 32, 64);
    qn[n] += __shfl_xor(qn[n], 16, 64);
    qn[n] += __shfl_xor(qn[n], 32, 64);
  }
  if (l < 16) {
#pragma unroll
    for (int n = 0; n < 4; ++n) {
      sRed[w][n * 16 + l][0] = sn[n];
      sRed[w][n * 16 + l][1] = qn[n];
    }
  }
  __syncthreads();
  if (t < 256) {
    int wcg = t >> 6;
    int idx = t & 63;
    float S = sRed[wcg][idx][0] + sRed[wcg + 4][idx][0];
    float Q = sRed[wcg][idx][1] + sRed[wcg + 4][idx][1];
    long o = ((long)t * gridDim.x + bxg) * 2;
    part[o] = S;
    part[o + 1] = Q;
  }
}

// ============ implicit-GEMM MFMA conv (layers 3-5) ============
template <int K>
__global__ __launch_bounds__(256)
void conv_mfma(const unsigned short* __restrict__ in, const unsigned short* __restrict__ wt,
               unsigned short* __restrict__ out, float* __restrict__ part,
               int Ci, int Co_pad, int Co_real,
               int Hi1, int Ho1, int NPIX1, int BX1, long inOff2, long outOff2,
               int Hi2, int Ho2, int NPIX2) {
  __shared__ __align__(16) unsigned short sA[2][128 * 32];
  __shared__ __align__(16) unsigned short sB[2][128 * 32];
  __shared__ int sOB[128];
  __shared__ float sRed[4][64][2];
  const int t = threadIdx.x;
  const int bxg = blockIdx.x;
  const bool br2 = bxg >= BX1;
  const int lbx = br2 ? bxg - BX1 : bxg;
  const unsigned short* inB = in + (br2 ? inOff2 : 0);
  unsigned short* outB = out + (br2 ? outOff2 : 0);
  const int Hi = br2 ? Hi2 : Hi1, Wi = Hi;
  const int Ho = br2 ? Ho2 : Ho1, Wo = Ho;
  const int NPIX = br2 ? NPIX2 : NPIX1;
  const int px0 = lbx * 128;
  const int co0 = blockIdx.y * 128;
  if (t < 128) {
    int g = px0 + t;
    int ob = -1;
    if (g < NPIX) {
      int n = g / (Ho * Wo);
      int r = g - n * Ho * Wo;
      int oy = r / Wo, ox = r - (r / Wo) * Wo;
      ob = ((n * Ho + oy) * Wo + ox) * Co_real;
    }
    sOB[t] = ob;
  }
  long rbase[2];
#pragma unroll
  for (int i = 0; i < 2; ++i) {
    int pxl = i * 64 + (t >> 2);
    int g = px0 + pxl;
    long rb = 0;
    if (g < NPIX) {
      int n = g / (Ho * Wo);
      int r = g - n * Ho * Wo;
      int oy = r / Wo, ox = r - (r / Wo) * Wo;
      rb = ((long)(n * Hi + oy) * Wi + ox) * Ci;
    }
    rbase[i] = rb;
  }
  const int seg8 = ((t & 3) ^ ((t >> 3) & 3)) * 8;
  const int colA = t >> 2;
  f32x4 acc[4][4];
  f32x4 zz = {0.f, 0.f, 0.f, 0.f};
#pragma unroll
  for (int m = 0; m < 4; ++m)
#pragma unroll
    for (int n = 0; n < 4; ++n) acc[m][n] = zz;
  const int w = t >> 6;
  const int l = t & 63;
  const int wpx = (w & 1) * 64, wco = (w >> 1) * 64;
  const int arow = wpx + (l & 15);
  const int brow = wco + (l & 15);
  const int q8s = (((l >> 4) ^ (((l & 15) >> 1) & 3)) * 8);
  int ci0 = 0, kx = 0, ky = 0;
  const int NK = (Ci >> 5) * K * K;

  auto stage = [&](int buf) {
    long koff = (long)(ky * Wi + kx) * Ci + ci0 + seg8;
    gload_lds16(inB + rbase[0] + koff, &sA[buf][t * 8]);
    gload_lds16(inB + rbase[1] + koff, &sA[buf][(256 + t) * 8]);
    long wbase = (long)((ky * K + kx) * Co_pad + co0) * Ci + ci0 + seg8;
    gload_lds16(wt + wbase + (long)colA * Ci, &sB[buf][t * 8]);
    gload_lds16(wt + wbase + (long)(64 + colA) * Ci, &sB[buf][(256 + t) * 8]);
    ci0 += 32;
    if (ci0 == Ci) { ci0 = 0; ++kx; if (kx == K) { kx = 0; ++ky; } }
  };

  stage(0);
  __syncthreads();
  int cur = 0;
#pragma unroll 1
  for (int kk = 0; kk < NK; ++kk) {
    if (kk + 1 < NK) stage(cur ^ 1);
    f16x8 av[4], bv[4];
#pragma unroll
    for (int m = 0; m < 4; ++m) av[m] = *(const f16x8*)&sA[cur][(arow + m * 16) * 32 + q8s];
#pragma unroll
    for (int n = 0; n < 4; ++n) bv[n] = *(const f16x8*)&sB[cur][(brow + n * 16) * 32 + q8s];
#pragma unroll
    for (int m = 0; m < 4; ++m)
#pragma unroll
      for (int n = 0; n < 4; ++n)
        acc[m][n] = __builtin_amdgcn_mfma_f32_16x16x32_f16(av[m], bv[n], acc[m][n], 0, 0, 0);
    __syncthreads();
    cur ^= 1;
  }
#pragma unroll
  for (int m = 0; m < 4; ++m) {
#pragma unroll
    for (int r = 0; r < 4; ++r) {
      int pxl = wpx + m * 16 + (l >> 4) * 4 + r;
      int ob = sOB[pxl];
#pragma unroll
      for (int n = 0; n < 4; ++n) {
        int co = co0 + wco + n * 16 + (l & 15);
        if (ob >= 0 && co < Co_real) outB[ob + co] = f2h(acc[m][n][r]);
      }
    }
  }
  float sn[4], qn[4];
#pragma unroll
  for (int n = 0; n < 4; ++n) { sn[n] = 0.f; qn[n] = 0.f; }
#pragma unroll
  for (int m = 0; m < 4; ++m) {
#pragma unroll
    for (int r = 0; r < 4; ++r) {
      int pxl = wpx + m * 16 + (l >> 4) * 4 + r;
      float msk = (px0 + pxl < NPIX) ? 1.f : 0.f;
#pragma unroll
      for (int n = 0; n < 4; ++n) {
        float v = acc[m][n][r] * msk;
        sn[n] += v;
        qn[n] = fmaf(v, v, qn[n]);
      }
    }
  }
#pragma unroll
  for (int n = 0; n < 4; ++n) {
    sn[n] += __shfl_xor(sn[n], 16, 64);
    sn[n] += __shfl_xor(sn[n], 32, 64);
    qn[n] += __shfl_xor(qn[n], 16, 64);
    qn[n] += __shfl_xor(qn[n], 32, 64);
  }
  if (l < 16) {
#pragma unroll
    for (int n = 0; n < 4; ++n) {
      sRed[w][n * 16 + l][0] = sn[n];
      sRed[w][n * 16 + l][1] = qn[n];
    }
  }
  __syncthreads();
  if (t < 128) {
    int wb = (t >> 6) << 1;
    int cl = t & 63;
    float S = sRed[wb][cl][0] + sRed[wb + 1][cl][0];
    float Q = sRed[wb][cl][1] + sRed[wb + 1][cl][1];
    long idx = ((long)(co0 + t) * gridDim.x + bxg) * 2;
    part[idx] = S;
    part[idx + 1] = Q;
  }
}

// ============ BN finalize, branch-merged ============
__global__ void bn_finalize(const float* __restrict__ part, const float* __restrict__ g,
                            const float* __restrict__ b, float* __restrict__ sc,
                            float* __restrict__ sh, int C, int BX1, int BXtot,
                            float cnt1, float cnt2) {
  const int cb = blockIdx.x;
  const bool br2 = cb >= C;
  const int c = br2 ? cb - C : cb;
  const int k0 = br2 ? BX1 : 0;
  const int k1 = br2 ? BXtot : BX1;
  const float cnt = br2 ? cnt2 : cnt1;
  const int t = threadIdx.x;
  float s = 0.f, q = 0.f;
  const float* pc = part + (long)c * BXtot * 2;
  for (int k = k0 + t; k < k1; k += 256) {
    s += pc[k * 2];
    q += pc[k * 2 + 1];
  }
  __shared__ float ss[256], qq[256];
  ss[t] = s; qq[t] = q;
  __syncthreads();
  for (int off = 128; off > 0; off >>= 1) {
    if (t < off) { ss[t] += ss[t + off]; qq[t] += qq[t + off]; }
    __syncthreads();
  }
  if (t == 0) {
    float m = ss[0] / cnt;
    float v = qq[0] / cnt - m * m;
    float r = rsqrtf(v + 1e-5f);
    float scl = r * g[c];
    int o = c + (br2 ? 256 : 0);
    sc[o] = scl;
    sh[o] = b[c] - m * scl;
  }
}

// ============ BN apply, branch-merged ============
template <bool RELU, bool OUTF32>
__global__ void bn_apply_k(const unsigned short* __restrict__ x, void* __restrict__ y,
                           const float* __restrict__ sc, const float* __restrict__ sh,
                           int C, long t81, long t82, long xOff2, long yOff2q4) {
  long i = (long)blockIdx.x * blockDim.x + threadIdx.x;
  if (i >= t81 + t82) return;
  const bool br2 = i >= t81;
  const long ii = br2 ? i - t81 : i;
  const int scO = br2 ? 256 : 0;
  const uint4 v = ((const uint4*)x + (br2 ? xOff2 : 0))[ii];
  int c0 = (int)((ii * 8) % C);
  const float4 s0 = *(const float4*)&sc[scO + c0];
  const float4 s1 = *(const float4*)&sc[scO + c0 + 4];
  const float4 h0 = *(const float4*)&sh[scO + c0];
  const float4 h1 = *(const float4*)&sh[scO + c0 + 4];
  float f[8];
  f[0] = h2f((unsigned short)(v.x & 0xffff)); f[1] = h2f((unsigned short)(v.x >> 16));
  f[2] = h2f((unsigned short)(v.y & 0xffff)); f[3] = h2f((unsigned short)(v.y >> 16));
  f[4] = h2f((unsigned short)(v.z & 0xffff)); f[5] = h2f((unsigned short)(v.z >> 16));
  f[6] = h2f((unsigned short)(v.w & 0xffff)); f[7] = h2f((unsigned short)(v.w >> 16));
  const float S[8] = {s0.x, s0.y, s0.z, s0.w, s1.x, s1.y, s1.z, s1.w};
  const float H[8] = {h0.x, h0.y, h0.z, h0.w, h1.x, h1.y, h1.z, h1.w};
#pragma unroll
  for (int j = 0; j < 8; ++j) {
    f[j] = fmaf(f[j], S[j], H[j]);
    if (RELU) f[j] = fmaxf(f[j], 0.f);
  }
  if (OUTF32) {
    float4* yb = (float4*)y + (br2 ? yOff2q4 : 0);
    float4 o0 = {f[0], f[1], f[2], f[3]}, o1 = {f[4], f[5], f[6], f[7]};
    yb[2 * ii] = o0;
    yb[2 * ii + 1] = o1;
  } else {
    uint4 o;
    o.x = (unsigned)f2h(f[0]) | ((unsigned)f2h(f[1]) << 16);
    o.y = (unsigned)f2h(f[2]) | ((unsigned)f2h(f[3]) << 16);
    o.z = (unsigned)f2h(f[4]) | ((unsigned)f2h(f[5]) << 16);
    o.w = (unsigned)f2h(f[6]) | ((unsigned)f2h(f[7]) << 16);
    ((uint4*)y + (br2 ? xOff2 : 0))[ii] = o;
  }
}

// ============ fused BN+ReLU+MaxPool 3x3 s2, branch-merged ============
__global__ void bn_pool_k(const unsigned short* __restrict__ in, unsigned short* __restrict__ out,
                          const float* __restrict__ sc, const float* __restrict__ sh,
                          int C8, int Hi1, int Ho1, long t81, long inOff2, long outOff2,
                          int Hi2, int Ho2, long t82) {
  long i = (long)blockIdx.x * blockDim.x + threadIdx.x;
  if (i >= t81 + t82) return;
  const bool br2 = i >= t81;
  const long ii = br2 ? i - t81 : i;
  const int Hi = br2 ? Hi2 : Hi1, Wi = Hi;
  const int Ho = br2 ? Ho2 : Ho1, Wo = Ho;
  const int scO = br2 ? 256 : 0;
  const uint4* inB = (const uint4*)in + (br2 ? inOff2 : 0);
  uint4* outB = (uint4*)out + (br2 ? outOff2 : 0);
  int cg = (int)(ii % C8);
  long r = ii / C8;
  int ox = (int)(r % Wo);
  r /= Wo;
  int oy = (int)(r % Ho);
  int n = (int)(r / Ho);
  const int c0 = cg * 8;
  const float4 s0 = *(const float4*)&sc[scO + c0];
  const float4 s1 = *(const float4*)&sc[scO + c0 + 4];
  const float4 h0 = *(const float4*)&sh[scO + c0];
  const float4 h1 = *(const float4*)&sh[scO + c0 + 4];
  const float S[8] = {s0.x, s0.y, s0.z, s0.w, s1.x, s1.y, s1.z, s1.w};
  const float H[8] = {h0.x, h0.y, h0.z, h0.w, h1.x, h1.y, h1.z, h1.w};
  const uint4* bp = inB + ((long)(n * Hi + 2 * oy) * Wi + 2 * ox) * C8 + cg;
  float m[8];
#pragma unroll
  for (int j = 0; j < 8; ++j) m[j] = -3.4e38f;
#pragma unroll
  for (int dy = 0; dy < 3; ++dy)
#pragma unroll
    for (int dx = 0; dx < 3; ++dx) {
      const uint4 v = bp[((long)dy * Wi + dx) * C8];
      float f[8];
      f[0] = h2f((unsigned short)(v.x & 0xffff)); f[1] = h2f((unsigned short)(v.x >> 16));
      f[2] = h2f((unsigned short)(v.y & 0xffff)); f[3] = h2f((unsigned short)(v.y >> 16));
      f[4] = h2f((unsigned short)(v.z & 0xffff)); f[5] = h2f((unsigned short)(v.z >> 16));
      f[6] = h2f((unsigned short)(v.w & 0xffff)); f[7] = h2f((unsigned short)(v.w >> 16));
#pragma unroll
      for (int j = 0; j < 8; ++j) {
        f[j] = fmaxf(fmaf(f[j], S[j], H[j]), 0.f);
        m[j] = fmaxf(m[j], f[j]);
      }
    }
  uint4 o;
  o.x = (unsigned)f2h(m[0]) | ((unsigned)f2h(m[1]) << 16);
  o.y = (unsigned)f2h(m[2]) | ((unsigned)f2h(m[3]) << 16);
  o.z = (unsigned)f2h(m[4]) | ((unsigned)f2h(m[5]) << 16);
  o.w = (unsigned)f2h(m[6]) | ((unsigned)f2h(m[7]) << 16);
  outB[ii] = o;
}

// ============ cross-correlation ============
__global__ void xcorr_part(const float* __restrict__ o1, const float* __restrict__ o2,
                           float* __restrict__ part) {
  const int p = blockIdx.x;
  const int b = blockIdx.y;
  const int oy = p / 17, ox = p - (p / 17) * 17;
  const float* o1b = o1 + (long)b * 22 * 22 * 128;
  const float* o2b = o2 + (long)b * 4608;
  float acc = 0.f;
  for (int i = threadIdx.x; i < 4608; i += 256) {
    int c = i & 127;
    int r = i >> 7;
    int kx = r % 6, ky = r / 6;
    acc = fmaf(o1b[((oy + ky) * 22 + ox + kx) * 128 + c], o2b[i], acc);
  }
#pragma unroll
  for (int off = 32; off > 0; off >>= 1) acc += __shfl_down(acc, off, 64);
  __shared__ float sh[4];
  const int lane = threadIdx.x & 63, wid = threadIdx.x >> 6;
  if (lane == 0) sh[wid] = acc;
  __syncthreads();
  if (threadIdx.x == 0) part[p * 32 + b] = sh[0] + sh[1] + sh[2] + sh[3];
}

__global__ void xcorr_out(const float* __restrict__ part, float* __restrict__ out, int total) {
  int i = blockIdx.x * 256 + threadIdx.x;
  if (i >= total) return;
  int p = i % 289;
  float s = 0.f;
  for (int b = 0; b < 32; ++b) s += part[p * 32 + b];
  out[i] = s * (1.f / 147456.f);
}

// ============ host ============
extern "C" void kernel_launch(void* const* d_in, const int* in_sizes, int n_in,
                              void* d_out, int out_size, void* d_ws, size_t ws_size,
                              hipStream_t stream) {
  (void)in_sizes; (void)n_in; (void)ws_size; (void)out_size;
  const float* input1 = (const float*)d_in[0];
  const float* input2 = (const float*)d_in[1];
  const float* cw[5];
  const float* bg[5];
  const float* bb[5];
  for (int i = 0; i < 5; ++i) {
    cw[i] = (const float*)d_in[2 + 2 * i];
    bg[i] = (const float*)d_in[12 + 2 * i];
    bb[i] = (const float*)d_in[13 + 2 * i];
  }
  const int H1a = 123, P1a = 61, H2a = 57, P2a = 28, H3a = 26, H4a = 24, H5a = 22;
  const int H1b = 59, P1b = 29, H2b = 25, P2b = 12, H3b = 10, H4b = 8, H5b = 6;
  auto NP = [](int h) { return 32 * h * h; };
  const int NP1a = NP(H1a), NP1b = NP(H1b);
  const int NP2a = NP(H2a), NP2b = NP(H2b);
  const int NP3a = NP(H3a), NP3b = NP(H3b);
  const int NP4a = NP(H4a), NP4b = NP(H4b);
  const int NP5a = NP(H5a), NP5b = NP(H5b);
  auto BX = [](int np) { return (np + 127) / 128; };

  char* p = (char*)d_ws;
  auto alloc = [&](size_t bytes) {
    char* r = p;
    p += (bytes + 255) & ~(size_t)255;
    return r;
  };
  unsigned short* P = (unsigned short*)alloc(((size_t)NP1a + NP1b) * 96 * 2);
  unsigned short* R = (unsigned short*)alloc(((size_t)NP(P1a) + NP(P1b)) * 96 * 2 + 262144);
  unsigned short* Q = (unsigned short*)alloc(((size_t)NP4a + NP4b) * 192 * 2);
  float* O12 = (float*)alloc(((size_t)NP5a + NP5b) * 128 * 4);
  unsigned short* I12h = (unsigned short*)alloc(((size_t)32 * 255 * 255 * 4 + (size_t)32 * 127 * 127 * 4) * 2 + 65536);
  unsigned short* W1h = (unsigned short*)alloc(17l * 128 * 32 * 2);
  unsigned short* W2 = (unsigned short*)alloc(256l * KPAD2 * 2);
  unsigned short* W3 = (unsigned short*)alloc(9l * 256 * 256 * 2);
  unsigned short* W4 = (unsigned short*)alloc(9l * 256 * 192 * 2);
  unsigned short* W5 = (unsigned short*)alloc(9l * 128 * 192 * 2);
  float* part = (float*)alloc(9000000);
  float* sc = (float*)alloc(512 * 4);
  float* sh = (float*)alloc(512 * 4);
  float* O1 = O12;
  float* O2 = O12 + (size_t)NP5a * 128;

  {
    long wt_tot = 17l * 128 * 32 + 256l * KPAD2 + 9l * 256 * 256 + 9l * 256 * 192 + 9l * 128 * 192;
    wt_all<<<(unsigned)((wt_tot + 255) / 256), 256, 0, stream>>>(cw[0], cw[1], cw[2], cw[3], cw[4],
                                                                 W1h, W2, W3, W4, W5);
    long in_tot = 32l * 255 * 255 + 32l * 127 * 127;
    in_all<<<(unsigned)((in_tot + 255) / 256), 256, 0, stream>>>(input1, input2, I12h,
                                                                 I12h + 32l * 255 * 255 * 4);
  }

  // ---- layer 1 ----
  {
    int BX1 = BX(NP1a), BXt = BX1 + BX(NP1b);
    conv1_mfma<<<(unsigned)BXt, 256, 0, stream>>>(I12h, W1h, P, part,
        255, H1a, NP1a, BX1, 32l * 255 * 255 * 4, (long)NP1a * 96,
        127, H1b, NP1b);
    bn_finalize<<<192, 256, 0, stream>>>(part, bg[0], bb[0], sc, sh, 96, BX1, BXt,
                                         (float)NP1a, (float)NP1b);
    long t81 = (long)NP(P1a) * 96 / 8, t82 = (long)NP(P1b) * 96 / 8;
    bn_pool_k<<<(unsigned)((t81 + t82 + 255) / 256), 256, 0, stream>>>(
        P, R, sc, sh, 12, H1a, P1a, t81, (long)NP1a * 96 / 8, t81, H1b, P1b, t82);
  }
  // ---- layer 2 (256x256 8-wave schedule, swizzled) ----
  {
    int BX1 = (NP2a + 255) / 256, BXt = BX1 + (NP2b + 255) / 256;
    conv2_big<<<(unsigned)BXt, 512, 0, stream>>>(R, W2, P, part,
        P1a, H2a, NP2a, BX1, (long)NP(P1a) * 96, (long)NP2a * 256,
        P1b, H2b, NP2b);
    bn_finalize<<<512, 256, 0, stream>>>(part, bg[1], bb[1], sc, sh, 256, BX1, BXt,
                                         (float)NP2a, (float)NP2b);
    long t81 = (long)NP(P2a) * 256 / 8, t82 = (long)NP(P2b) * 256 / 8;
    bn_pool_k<<<(unsigned)((t81 + t82 + 255) / 256), 256, 0, stream>>>(
        P, R, sc, sh, 32, H2a, P2a, t81, (long)NP2a * 256 / 8, t81, H2b, P2b, t82);
  }
  // ---- layer 3 ----
  {
    int BX1 = BX(NP3a), BXt = BX1 + BX(NP3b);
    dim3 g((unsigned)BXt, 2);
    conv_mfma<3><<<g, 256, 0, stream>>>(R, W3, P, part, 256, 256, 192,
        P2a, H3a, NP3a, BX1, (long)NP(P2a) * 256, (long)NP3a * 192,
        P2b, H3b, NP3b);
    bn_finalize<<<384, 256, 0, stream>>>(part, bg[2], bb[2], sc, sh, 192, BX1, BXt,
                                         (float)NP3a, (float)NP3b);
    long t81 = (long)NP3a * 192 / 8, t82 = (long)NP3b * 192 / 8;
    bn_apply_k<true, false><<<(unsigned)((t81 + t82 + 255) / 256), 256, 0, stream>>>(
        P, P, sc, sh, 192, t81, t82, t81, 0);
  }
  // ---- layer 4 ----
  {
    int BX1 = BX(NP4a), BXt = BX1 + BX(NP4b);
    dim3 g((unsigned)BXt, 2);
    conv_mfma<3><<<g, 256, 0, stream>>>(P, W4, Q, part, 192, 256, 192,
        H3a, H4a, NP4a, BX1, (long)NP3a * 192, (long)NP4a * 192,
        H3b, H4b, NP4b);
    bn_finalize<<<384, 256, 0, stream>>>(part, bg[3], bb[3], sc, sh, 192, BX1, BXt,
                                         (float)NP4a, (float)NP4b);
    long t81 = (long)NP4a * 192 / 8, t82 = (long)NP4b * 192 / 8;
    bn_apply_k<true, false><<<(unsigned)((t81 + t82 + 255) / 256), 256, 0, stream>>>(
        Q, Q, sc, sh, 192, t81, t82, t81, 0);
  }
  // ---- layer 5 ----
  {
    int BX1 = BX(NP5a), BXt = BX1 + BX(NP5b);
    dim3 g((unsigned)BXt, 1);
    conv_mfma<3><<<g, 256, 0, stream>>>(Q, W5, P, part, 192, 128, 128,
        H4a, H5a, NP5a, BX1, (long)NP4a * 192, (long)NP5a * 128,
        H4b, H5b, NP5b);
    bn_finalize<<<256, 256, 0, stream>>>(part, bg[4], bb[4], sc, sh, 128, BX1, BXt,
                                         (float)NP5a, (float)NP5b);
    long t81 = (long)NP5a * 128 / 8, t82 = (long)NP5b * 128 / 8;
    bn_apply_k<false, true><<<(unsigned)((t81 + t82 + 255) / 256), 256, 0, stream>>>(
        P, O12, sc, sh, 128, t81, t82, t81, (long)NP5a * 128 / 4);
  }

  xcorr_part<<<dim3(289, 32), 256, 0, stream>>>(O1, O2, part);
  xcorr_out<<<(9248 + 255) / 256, 256, 0, stream>>>(part, (float*)d_out, 9248);
}

// Round 14
// 550.641 us; speedup vs baseline: 1.1258x; 1.1194x over previous
//
#include <hip/hip_runtime.h>
#include <hip/hip_bf16.h>
#include <cstdint>
#include <cstddef>

typedef __attribute__((ext_vector_type(8))) _Float16 f16x8;
typedef __attribute__((ext_vector_type(4))) float f32x4;

__device__ __forceinline__ float h2f(unsigned short u) {
  union { unsigned short s; _Float16 h; } x; x.s = u; return (float)x.h;
}
__device__ __forceinline__ unsigned short f2h(float f) {
  union { unsigned short s; _Float16 h; } x; x.h = (_Float16)f; return x.s;
}
__device__ __forceinline__ void gload_lds16(const void* g, void* l) {
  __builtin_amdgcn_global_load_lds((const __attribute__((address_space(1))) unsigned int*)g,
                                   (__attribute__((address_space(3))) unsigned int*)l, 16, 0, 0);
}

// ============ merged input transform ============
__global__ void in_all(const float* __restrict__ in1, const float* __restrict__ in2,
                       unsigned short* __restrict__ o1, unsigned short* __restrict__ o2) {
  int i = blockIdx.x * 256 + threadIdx.x;
  const int p1 = 32 * 255 * 255;
  const int p2 = 32 * 127 * 127;
  const float* in;
  unsigned short* o;
  int HW;
  if (i < p1) {
    in = in1; o = o1; HW = 255 * 255;
  } else if (i < p1 + p2) {
    i -= p1; in = in2; o = o2; HW = 127 * 127;
  } else return;
  int n = i / HW;
  int r = i - n * HW;
  const float* p = in + (long)n * 3 * HW + r;
  uint2 v;
  v.x = (unsigned)f2h(p[0]) | ((unsigned)f2h(p[HW]) << 16);
  v.y = (unsigned)f2h(p[2 * HW]);
  ((uint2*)o)[i] = v;
}

// ============ merged weight transform ============
__device__ __forceinline__ void wtx(const float* __restrict__ w, unsigned short* __restrict__ o,
                                    long i, int Co, int Co_pad, int Ci, int KK) {
  int ci = (int)(i % Ci);
  long r = i / Ci;
  int co = (int)(r % Co_pad);
  int rk = (int)(r / Co_pad);
  float v = 0.f;
  if (co < Co) v = w[((long)co * Ci + ci) * KK + rk];
  o[i] = f2h(v);
}
__global__ void wt_all(const float* __restrict__ w1, const float* __restrict__ w2,
                       const float* __restrict__ w3, const float* __restrict__ w4,
                       const float* __restrict__ w5,
                       unsigned short* __restrict__ W1h, unsigned short* __restrict__ W2,
                       unsigned short* __restrict__ W3, unsigned short* __restrict__ W4,
                       unsigned short* __restrict__ W5) {
  long i = (long)blockIdx.x * 256 + threadIdx.x;
  const long t1 = 17 * 128 * 32;
  const long t2 = 25l * 256 * 96;
  const long t3 = 9l * 192 * 256;
  const long t4 = 9l * 192 * 192;
  const long t5 = 9l * 128 * 192;
  if (i < t1) {
    int j = (int)(i & 31);
    int r = (int)(i >> 5);
    int co = r & 127;
    int kk = r >> 7;
    int run = kk * 4 + (j >> 3);
    int ky = run / 6;
    int e = (run - ky * 6) * 8 + (j & 7);
    int kx = e >> 2, c = e & 3;
    float v = 0.f;
    if (ky < 11 && kx < 11 && c < 3 && co < 96)
      v = w1[((co * 3 + c) * 11 + ky) * 11 + kx];
    W1h[i] = f2h(v);
  } else if (i < t1 + t2) {
    wtx(w2, W2, i - t1, 256, 256, 96, 25);
  } else if (i < t1 + t2 + t3) {
    wtx(w3, W3, i - t1 - t2, 192, 192, 256, 9);
  } else if (i < t1 + t2 + t3 + t4) {
    wtx(w4, W4, i - t1 - t2 - t3, 192, 192, 192, 9);
  } else if (i < t1 + t2 + t3 + t4 + t5) {
    wtx(w5, W5, i - t1 - t2 - t3 - t4, 128, 128, 192, 9);
  }
}

// ============ conv1 MFMA: 128px x 96co (NB=3), dbuf + swizzle + fused stats ============
__global__ __launch_bounds__(256)
void conv1_mfma(const unsigned short* __restrict__ in, const unsigned short* __restrict__ wt,
                unsigned short* __restrict__ out, float* __restrict__ part,
                int Hi1, int Ho1, int NPIX1, int BX1, long inOff2, long outOff2,
                int Hi2, int Ho2, int NPIX2) {
  __shared__ __align__(16) unsigned short sA[2][128 * 32];
  __shared__ __align__(16) unsigned short sB[2][128 * 32];
  __shared__ int sOB[128];
  __shared__ float sRed[4][48][2];
  const int t = threadIdx.x;
  const int bxg = blockIdx.x;
  const bool br2 = bxg >= BX1;
  const int lbx = br2 ? bxg - BX1 : bxg;
  const unsigned short* inB = in + (br2 ? inOff2 : 0);
  unsigned short* outB = out + (br2 ? outOff2 : 0);
  const int Hi = br2 ? Hi2 : Hi1, Wi = Hi;
  const int Ho = br2 ? Ho2 : Ho1, Wo = Ho;
  const int NPIX = br2 ? NPIX2 : NPIX1;
  const int px0 = lbx * 128;
  if (t < 128) {
    int g = px0 + t;
    int ob = -1;
    if (g < NPIX) {
      int n = g / (Ho * Wo);
      int r = g - n * Ho * Wo;
      int oy = r / Wo, ox = r - (r / Wo) * Wo;
      ob = ((n * Ho + oy) * Wo + ox) * 96;
    }
    sOB[t] = ob;
  }
  long rbase[2];
#pragma unroll
  for (int i = 0; i < 2; ++i) {
    int pxl = i * 64 + (t >> 2);
    int g = px0 + pxl;
    long rb = 0;
    if (g < NPIX) {
      int n = g / (Ho * Wo);
      int r = g - n * Ho * Wo;
      int oy = r / Wo, ox = r - (r / Wo) * Wo;
      rb = ((long)(n * Hi + 2 * oy) * Wi + 2 * ox) * 4;
    }
    rbase[i] = rb;
  }
  const int swz = (t & 3) ^ ((t >> 3) & 3);
  const int W4 = Wi * 4;
  f32x4 acc[4][3];
  f32x4 zz = {0.f, 0.f, 0.f, 0.f};
#pragma unroll
  for (int m = 0; m < 4; ++m)
#pragma unroll
    for (int n = 0; n < 3; ++n) acc[m][n] = zz;
  const int w = t >> 6;
  const int l = t & 63;
  const int wpx = (w & 1) * 64, wco = (w >> 1) * 48;
  const int arow = wpx + (l & 15);
  const int brow = wco + (l & 15);
  const int q8s = (((l >> 4) ^ (((l & 15) >> 1) & 3)) * 8);

  auto stage = [&](int buf, int kk) {
    int run = kk * 4 + swz;
    int ky = run / 6;
    int e0 = (run - ky * 6) * 8;
    long koff = (long)ky * W4 + e0;
    gload_lds16(inB + rbase[0] + koff, &sA[buf][t * 8]);
    gload_lds16(inB + rbase[1] + koff, &sA[buf][(256 + t) * 8]);
    const unsigned short* wp = wt + (long)kk * 4096;
    gload_lds16(wp + (t >> 2) * 32 + swz * 8, &sB[buf][t * 8]);
    if (t < 128)
      gload_lds16(wp + 2048 + (t >> 2) * 32 + swz * 8, &sB[buf][(256 + t) * 8]);
  };

  stage(0, 0);
  __syncthreads();
  int cur = 0;
#pragma unroll 1
  for (int kk = 0; kk < 17; ++kk) {
    if (kk + 1 < 17) stage(cur ^ 1, kk + 1);
    f16x8 av[4], bv[3];
#pragma unroll
    for (int m = 0; m < 4; ++m) av[m] = *(const f16x8*)&sA[cur][(arow + m * 16) * 32 + q8s];
#pragma unroll
    for (int n = 0; n < 3; ++n) bv[n] = *(const f16x8*)&sB[cur][(brow + n * 16) * 32 + q8s];
#pragma unroll
    for (int m = 0; m < 4; ++m)
#pragma unroll
      for (int n = 0; n < 3; ++n)
        acc[m][n] = __builtin_amdgcn_mfma_f32_16x16x32_f16(av[m], bv[n], acc[m][n], 0, 0, 0);
    __syncthreads();
    cur ^= 1;
  }
#pragma unroll
  for (int m = 0; m < 4; ++m) {
#pragma unroll
    for (int r = 0; r < 4; ++r) {
      int pxl = wpx + m * 16 + (l >> 4) * 4 + r;
      int ob = sOB[pxl];
#pragma unroll
      for (int n = 0; n < 3; ++n) {
        int co = wco + n * 16 + (l & 15);
        if (ob >= 0) outB[ob + co] = f2h(acc[m][n][r]);
      }
    }
  }
  float sn[3], qn[3];
#pragma unroll
  for (int n = 0; n < 3; ++n) { sn[n] = 0.f; qn[n] = 0.f; }
#pragma unroll
  for (int m = 0; m < 4; ++m) {
#pragma unroll
    for (int r = 0; r < 4; ++r) {
      int pxl = wpx + m * 16 + (l >> 4) * 4 + r;
      float msk = (px0 + pxl < NPIX) ? 1.f : 0.f;
#pragma unroll
      for (int n = 0; n < 3; ++n) {
        float v = acc[m][n][r] * msk;
        sn[n] += v;
        qn[n] = fmaf(v, v, qn[n]);
      }
    }
  }
#pragma unroll
  for (int n = 0; n < 3; ++n) {
    sn[n] += __shfl_xor(sn[n], 16, 64);
    sn[n] += __shfl_xor(sn[n], 32, 64);
    qn[n] += __shfl_xor(qn[n], 16, 64);
    qn[n] += __shfl_xor(qn[n], 32, 64);
  }
  if (l < 16) {
#pragma unroll
    for (int n = 0; n < 3; ++n) {
      sRed[w][n * 16 + l][0] = sn[n];
      sRed[w][n * 16 + l][1] = qn[n];
    }
  }
  __syncthreads();
  if (t < 96) {
    int g = t / 48;
    int cl = t - g * 48;
    float S = sRed[2 * g][cl][0] + sRed[2 * g + 1][cl][0];
    float Q = sRed[2 * g][cl][1] + sRed[2 * g + 1][cl][1];
    long idx = ((long)t * gridDim.x + bxg) * 2;
    part[idx] = S;
    part[idx + 1] = Q;
  }
}

// ============ implicit-GEMM MFMA conv: 128px x NB*32co per block ============
template <int K, int NB>
__global__ __launch_bounds__(256)
void conv_mfma(const unsigned short* __restrict__ in, const unsigned short* __restrict__ wt,
               unsigned short* __restrict__ out, float* __restrict__ part,
               int Ci, int Co_pad, int Co_real,
               int Hi1, int Ho1, int NPIX1, int BX1, long inOff2, long outOff2,
               int Hi2, int Ho2, int NPIX2) {
  __shared__ __align__(16) unsigned short sA[2][128 * 32];
  __shared__ __align__(16) unsigned short sB[2][128 * 32];
  __shared__ int sOB[128];
  __shared__ float sRed[4][NB * 16][2];
  const int t = threadIdx.x;
  const int bxg = blockIdx.x;
  const bool br2 = bxg >= BX1;
  const int lbx = br2 ? bxg - BX1 : bxg;
  const unsigned short* inB = in + (br2 ? inOff2 : 0);
  unsigned short* outB = out + (br2 ? outOff2 : 0);
  const int Hi = br2 ? Hi2 : Hi1, Wi = Hi;
  const int Ho = br2 ? Ho2 : Ho1, Wo = Ho;
  const int NPIX = br2 ? NPIX2 : NPIX1;
  const int px0 = lbx * 128;
  const int co0 = blockIdx.y * (NB * 32);
  if (t < 128) {
    int g = px0 + t;
    int ob = -1;
    if (g < NPIX) {
      int n = g / (Ho * Wo);
      int r = g - n * Ho * Wo;
      int oy = r / Wo, ox = r - (r / Wo) * Wo;
      ob = ((n * Ho + oy) * Wo + ox) * Co_real;
    }
    sOB[t] = ob;
  }
  long rbase[2];
#pragma unroll
  for (int i = 0; i < 2; ++i) {
    int pxl = i * 64 + (t >> 2);
    int g = px0 + pxl;
    long rb = 0;
    if (g < NPIX) {
      int n = g / (Ho * Wo);
      int r = g - n * Ho * Wo;
      int oy = r / Wo, ox = r - (r / Wo) * Wo;
      rb = ((long)(n * Hi + oy) * Wi + ox) * Ci;
    }
    rbase[i] = rb;
  }
  const int seg8 = ((t & 3) ^ ((t >> 3) & 3)) * 8;
  const int colA = t >> 2;
  f32x4 acc[4][NB];
  f32x4 zz = {0.f, 0.f, 0.f, 0.f};
#pragma unroll
  for (int m = 0; m < 4; ++m)
#pragma unroll
    for (int n = 0; n < NB; ++n) acc[m][n] = zz;
  const int w = t >> 6;
  const int l = t & 63;
  const int wpx = (w & 1) * 64, wco = (w >> 1) * (NB * 16);
  const int arow = wpx + (l & 15);
  const int brow = wco + (l & 15);
  const int q8s = (((l >> 4) ^ (((l & 15) >> 1) & 3)) * 8);
  int ci0 = 0, kx = 0, ky = 0;
  const int NK = (Ci >> 5) * K * K;

  auto stage = [&](int buf) {
    long koff = (long)(ky * Wi + kx) * Ci + ci0 + seg8;
    gload_lds16(inB + rbase[0] + koff, &sA[buf][t * 8]);
    gload_lds16(inB + rbase[1] + koff, &sA[buf][(256 + t) * 8]);
    long wbase = (long)((ky * K + kx) * Co_pad + co0) * Ci + ci0 + seg8;
    gload_lds16(wt + wbase + (long)colA * Ci, &sB[buf][t * 8]);
    if (NB == 4 || t < 128)
      gload_lds16(wt + wbase + (long)(64 + colA) * Ci, &sB[buf][(256 + t) * 8]);
    ci0 += 32;
    if (ci0 == Ci) { ci0 = 0; ++kx; if (kx == K) { kx = 0; ++ky; } }
  };

  stage(0);
  __syncthreads();
  int cur = 0;
#pragma unroll 1
  for (int kk = 0; kk < NK; ++kk) {
    if (kk + 1 < NK) stage(cur ^ 1);
    f16x8 av[4], bv[NB];
#pragma unroll
    for (int m = 0; m < 4; ++m) av[m] = *(const f16x8*)&sA[cur][(arow + m * 16) * 32 + q8s];
#pragma unroll
    for (int n = 0; n < NB; ++n) bv[n] = *(const f16x8*)&sB[cur][(brow + n * 16) * 32 + q8s];
#pragma unroll
    for (int m = 0; m < 4; ++m)
#pragma unroll
      for (int n = 0; n < NB; ++n)
        acc[m][n] = __builtin_amdgcn_mfma_f32_16x16x32_f16(av[m], bv[n], acc[m][n], 0, 0, 0);
    __syncthreads();
    cur ^= 1;
  }
#pragma unroll
  for (int m = 0; m < 4; ++m) {
#pragma unroll
    for (int r = 0; r < 4; ++r) {
      int pxl = wpx + m * 16 + (l >> 4) * 4 + r;
      int ob = sOB[pxl];
#pragma unroll
      for (int n = 0; n < NB; ++n) {
        int co = co0 + wco + n * 16 + (l & 15);
        if (ob >= 0 && co < Co_real) outB[ob + co] = f2h(acc[m][n][r]);
      }
    }
  }
  float sn[NB], qn[NB];
#pragma unroll
  for (int n = 0; n < NB; ++n) { sn[n] = 0.f; qn[n] = 0.f; }
#pragma unroll
  for (int m = 0; m < 4; ++m) {
#pragma unroll
    for (int r = 0; r < 4; ++r) {
      int pxl = wpx + m * 16 + (l >> 4) * 4 + r;
      float msk = (px0 + pxl < NPIX) ? 1.f : 0.f;
#pragma unroll
      for (int n = 0; n < NB; ++n) {
        float v = acc[m][n][r] * msk;
        sn[n] += v;
        qn[n] = fmaf(v, v, qn[n]);
      }
    }
  }
#pragma unroll
  for (int n = 0; n < NB; ++n) {
    sn[n] += __shfl_xor(sn[n], 16, 64);
    sn[n] += __shfl_xor(sn[n], 32, 64);
    qn[n] += __shfl_xor(qn[n], 16, 64);
    qn[n] += __shfl_xor(qn[n], 32, 64);
  }
  if (l < 16) {
#pragma unroll
    for (int n = 0; n < NB; ++n) {
      sRed[w][n * 16 + l][0] = sn[n];
      sRed[w][n * 16 + l][1] = qn[n];
    }
  }
  __syncthreads();
  if (t < NB * 32) {
    int g = t / (NB * 16);
    int cl = t - g * (NB * 16);
    float S = sRed[2 * g][cl][0] + sRed[2 * g + 1][cl][0];
    float Q = sRed[2 * g][cl][1] + sRed[2 * g + 1][cl][1];
    long idx = ((long)(co0 + t) * gridDim.x + bxg) * 2;
    part[idx] = S;
    part[idx + 1] = Q;
  }
}

// ============ BN finalize, branch-merged ============
__global__ void bn_finalize(const float* __restrict__ part, const float* __restrict__ g,
                            const float* __restrict__ b, float* __restrict__ sc,
                            float* __restrict__ sh, int C, int BX1, int BXtot,
                            float cnt1, float cnt2) {
  const int cb = blockIdx.x;
  const bool br2 = cb >= C;
  const int c = br2 ? cb - C : cb;
  const int k0 = br2 ? BX1 : 0;
  const int k1 = br2 ? BXtot : BX1;
  const float cnt = br2 ? cnt2 : cnt1;
  const int t = threadIdx.x;
  float s = 0.f, q = 0.f;
  const float* pc = part + (long)c * BXtot * 2;
  for (int k = k0 + t; k < k1; k += 256) {
    s += pc[k * 2];
    q += pc[k * 2 + 1];
  }
  __shared__ float ss[256], qq[256];
  ss[t] = s; qq[t] = q;
  __syncthreads();
  for (int off = 128; off > 0; off >>= 1) {
    if (t < off) { ss[t] += ss[t + off]; qq[t] += qq[t + off]; }
    __syncthreads();
  }
  if (t == 0) {
    float m = ss[0] / cnt;
    float v = qq[0] / cnt - m * m;
    float r = rsqrtf(v + 1e-5f);
    float scl = r * g[c];
    int o = c + (br2 ? 256 : 0);
    sc[o] = scl;
    sh[o] = b[c] - m * scl;
  }
}

// ============ BN apply, branch-merged ============
template <bool RELU, bool OUTF32>
__global__ void bn_apply_k(const unsigned short* __restrict__ x, void* __restrict__ y,
                           const float* __restrict__ sc, const float* __restrict__ sh,
                           int C, long t81, long t82, long xOff2, long yOff2q4) {
  long i = (long)blockIdx.x * blockDim.x + threadIdx.x;
  if (i >= t81 + t82) return;
  const bool br2 = i >= t81;
  const long ii = br2 ? i - t81 : i;
  const int scO = br2 ? 256 : 0;
  const uint4 v = ((const uint4*)x + (br2 ? xOff2 : 0))[ii];
  int c0 = (int)((ii * 8) % C);
  const float4 s0 = *(const float4*)&sc[scO + c0];
  const float4 s1 = *(const float4*)&sc[scO + c0 + 4];
  const float4 h0 = *(const float4*)&sh[scO + c0];
  const float4 h1 = *(const float4*)&sh[scO + c0 + 4];
  float f[8];
  f[0] = h2f((unsigned short)(v.x & 0xffff)); f[1] = h2f((unsigned short)(v.x >> 16));
  f[2] = h2f((unsigned short)(v.y & 0xffff)); f[3] = h2f((unsigned short)(v.y >> 16));
  f[4] = h2f((unsigned short)(v.z & 0xffff)); f[5] = h2f((unsigned short)(v.z >> 16));
  f[6] = h2f((unsigned short)(v.w & 0xffff)); f[7] = h2f((unsigned short)(v.w >> 16));
  const float S[8] = {s0.x, s0.y, s0.z, s0.w, s1.x, s1.y, s1.z, s1.w};
  const float H[8] = {h0.x, h0.y, h0.z, h0.w, h1.x, h1.y, h1.z, h1.w};
#pragma unroll
  for (int j = 0; j < 8; ++j) {
    f[j] = fmaf(f[j], S[j], H[j]);
    if (RELU) f[j] = fmaxf(f[j], 0.f);
  }
  if (OUTF32) {
    float4* yb = (float4*)y + (br2 ? yOff2q4 : 0);
    float4 o0 = {f[0], f[1], f[2], f[3]}, o1 = {f[4], f[5], f[6], f[7]};
    yb[2 * ii] = o0;
    yb[2 * ii + 1] = o1;
  } else {
    uint4 o;
    o.x = (unsigned)f2h(f[0]) | ((unsigned)f2h(f[1]) << 16);
    o.y = (unsigned)f2h(f[2]) | ((unsigned)f2h(f[3]) << 16);
    o.z = (unsigned)f2h(f[4]) | ((unsigned)f2h(f[5]) << 16);
    o.w = (unsigned)f2h(f[6]) | ((unsigned)f2h(f[7]) << 16);
    ((uint4*)y + (br2 ? xOff2 : 0))[ii] = o;
  }
}

// ============ fused BN+ReLU+MaxPool 3x3 s2, branch-merged ============
__global__ void bn_pool_k(const unsigned short* __restrict__ in, unsigned short* __restrict__ out,
                          const float* __restrict__ sc, const float* __restrict__ sh,
                          int C8, int Hi1, int Ho1, long t81, long inOff2, long outOff2,
                          int Hi2, int Ho2, long t82) {
  long i = (long)blockIdx.x * blockDim.x + threadIdx.x;
  if (i >= t81 + t82) return;
  const bool br2 = i >= t81;
  const long ii = br2 ? i - t81 : i;
  const int Hi = br2 ? Hi2 : Hi1, Wi = Hi;
  const int Ho = br2 ? Ho2 : Ho1, Wo = Ho;
  const int scO = br2 ? 256 : 0;
  const uint4* inB = (const uint4*)in + (br2 ? inOff2 : 0);
  uint4* outB = (uint4*)out + (br2 ? outOff2 : 0);
  int cg = (int)(ii % C8);
  long r = ii / C8;
  int ox = (int)(r % Wo);
  r /= Wo;
  int oy = (int)(r % Ho);
  int n = (int)(r / Ho);
  const int c0 = cg * 8;
  const float4 s0 = *(const float4*)&sc[scO + c0];
  const float4 s1 = *(const float4*)&sc[scO + c0 + 4];
  const float4 h0 = *(const float4*)&sh[scO + c0];
  const float4 h1 = *(const float4*)&sh[scO + c0 + 4];
  const float S[8] = {s0.x, s0.y, s0.z, s0.w, s1.x, s1.y, s1.z, s1.w};
  const float H[8] = {h0.x, h0.y, h0.z, h0.w, h1.x, h1.y, h1.z, h1.w};
  const uint4* bp = inB + ((long)(n * Hi + 2 * oy) * Wi + 2 * ox) * C8 + cg;
  float m[8];
#pragma unroll
  for (int j = 0; j < 8; ++j) m[j] = -3.4e38f;
#pragma unroll
  for (int dy = 0; dy < 3; ++dy)
#pragma unroll
    for (int dx = 0; dx < 3; ++dx) {
      const uint4 v = bp[((long)dy * Wi + dx) * C8];
      float f[8];
      f[0] = h2f((unsigned short)(v.x & 0xffff)); f[1] = h2f((unsigned short)(v.x >> 16));
      f[2] = h2f((unsigned short)(v.y & 0xffff)); f[3] = h2f((unsigned short)(v.y >> 16));
      f[4] = h2f((unsigned short)(v.z & 0xffff)); f[5] = h2f((unsigned short)(v.z >> 16));
      f[6] = h2f((unsigned short)(v.w & 0xffff)); f[7] = h2f((unsigned short)(v.w >> 16));
#pragma unroll
      for (int j = 0; j < 8; ++j) {
        f[j] = fmaxf(fmaf(f[j], S[j], H[j]), 0.f);
        m[j] = fmaxf(m[j], f[j]);
      }
    }
  uint4 o;
  o.x = (unsigned)f2h(m[0]) | ((unsigned)f2h(m[1]) << 16);
  o.y = (unsigned)f2h(m[2]) | ((unsigned)f2h(m[3]) << 16);
  o.z = (unsigned)f2h(m[4]) | ((unsigned)f2h(m[5]) << 16);
  o.w = (unsigned)f2h(m[6]) | ((unsigned)f2h(m[7]) << 16);
  outB[ii] = o;
}

// ============ cross-correlation ============
__global__ void xcorr_part(const float* __restrict__ o1, const float* __restrict__ o2,
                           float* __restrict__ part) {
  const int p = blockIdx.x;
  const int b = blockIdx.y;
  const int oy = p / 17, ox = p - (p / 17) * 17;
  const float* o1b = o1 + (long)b * 22 * 22 * 128;
  const float* o2b = o2 + (long)b * 4608;
  float acc = 0.f;
  for (int i = threadIdx.x; i < 4608; i += 256) {
    int c = i & 127;
    int r = i >> 7;
    int kx = r % 6, ky = r / 6;
    acc = fmaf(o1b[((oy + ky) * 22 + ox + kx) * 128 + c], o2b[i], acc);
  }
#pragma unroll
  for (int off = 32; off > 0; off >>= 1) acc += __shfl_down(acc, off, 64);
  __shared__ float sh[4];
  const int lane = threadIdx.x & 63, wid = threadIdx.x >> 6;
  if (lane == 0) sh[wid] = acc;
  __syncthreads();
  if (threadIdx.x == 0) part[p * 32 + b] = sh[0] + sh[1] + sh[2] + sh[3];
}

__global__ void xcorr_out(const float* __restrict__ part, float* __restrict__ out, int total) {
  int i = blockIdx.x * 256 + threadIdx.x;
  if (i >= total) return;
  int p = i % 289;
  float s = 0.f;
  for (int b = 0; b < 32; ++b) s += part[p * 32 + b];
  out[i] = s * (1.f / 147456.f);
}

// ============ host ============
extern "C" void kernel_launch(void* const* d_in, const int* in_sizes, int n_in,
                              void* d_out, int out_size, void* d_ws, size_t ws_size,
                              hipStream_t stream) {
  (void)in_sizes; (void)n_in; (void)ws_size; (void)out_size;
  const float* input1 = (const float*)d_in[0];
  const float* input2 = (const float*)d_in[1];
  const float* cw[5];
  const float* bg[5];
  const float* bb[5];
  for (int i = 0; i < 5; ++i) {
    cw[i] = (const float*)d_in[2 + 2 * i];
    bg[i] = (const float*)d_in[12 + 2 * i];
    bb[i] = (const float*)d_in[13 + 2 * i];
  }
  const int H1a = 123, P1a = 61, H2a = 57, P2a = 28, H3a = 26, H4a = 24, H5a = 22;
  const int H1b = 59, P1b = 29, H2b = 25, P2b = 12, H3b = 10, H4b = 8, H5b = 6;
  auto NP = [](int h) { return 32 * h * h; };
  const int NP1a = NP(H1a), NP1b = NP(H1b);
  const int NP2a = NP(H2a), NP2b = NP(H2b);
  const int NP3a = NP(H3a), NP3b = NP(H3b);
  const int NP4a = NP(H4a), NP4b = NP(H4b);
  const int NP5a = NP(H5a), NP5b = NP(H5b);
  auto BX = [](int np) { return (np + 127) / 128; };

  char* p = (char*)d_ws;
  auto alloc = [&](size_t bytes) {
    char* r = p;
    p += (bytes + 255) & ~(size_t)255;
    return r;
  };
  unsigned short* P = (unsigned short*)alloc(((size_t)NP1a + NP1b) * 96 * 2);
  unsigned short* R = (unsigned short*)alloc(((size_t)NP(P1a) + NP(P1b)) * 96 * 2 + 262144);
  unsigned short* Q = (unsigned short*)alloc(((size_t)NP4a + NP4b) * 192 * 2);
  float* O12 = (float*)alloc(((size_t)NP5a + NP5b) * 128 * 4);
  unsigned short* I12h = (unsigned short*)alloc(((size_t)32 * 255 * 255 * 4 + (size_t)32 * 127 * 127 * 4) * 2 + 65536);
  unsigned short* W1h = (unsigned short*)alloc(17l * 128 * 32 * 2);
  unsigned short* W2 = (unsigned short*)alloc(25l * 256 * 96 * 2);
  unsigned short* W3 = (unsigned short*)alloc(9l * 192 * 256 * 2);
  unsigned short* W4 = (unsigned short*)alloc(9l * 192 * 192 * 2);
  unsigned short* W5 = (unsigned short*)alloc(9l * 128 * 192 * 2);
  float* part = (float*)alloc(9000000);
  float* sc = (float*)alloc(512 * 4);
  float* sh = (float*)alloc(512 * 4);
  float* O1 = O12;
  float* O2 = O12 + (size_t)NP5a * 128;

  {
    long wt_tot = 17l * 128 * 32 + 25l * 256 * 96 + 9l * 192 * 256 + 9l * 192 * 192 + 9l * 128 * 192;
    wt_all<<<(unsigned)((wt_tot + 255) / 256), 256, 0, stream>>>(cw[0], cw[1], cw[2], cw[3], cw[4],
                                                                 W1h, W2, W3, W4, W5);
    long in_tot = 32l * 255 * 255 + 32l * 127 * 127;
    in_all<<<(unsigned)((in_tot + 255) / 256), 256, 0, stream>>>(input1, input2, I12h,
                                                                 I12h + 32l * 255 * 255 * 4);
  }

  // ---- layer 1 (96-co tiles) ----
  {
    int BX1 = BX(NP1a), BXt = BX1 + BX(NP1b);
    conv1_mfma<<<(unsigned)BXt, 256, 0, stream>>>(I12h, W1h, P, part,
        255, H1a, NP1a, BX1, 32l * 255 * 255 * 4, (long)NP1a * 96,
        127, H1b, NP1b);
    bn_finalize<<<192, 256, 0, stream>>>(part, bg[0], bb[0], sc, sh, 96, BX1, BXt,
                                         (float)NP1a, (float)NP1b);
    long t81 = (long)NP(P1a) * 96 / 8, t82 = (long)NP(P1b) * 96 / 8;
    bn_pool_k<<<(unsigned)((t81 + t82 + 255) / 256), 256, 0, stream>>>(
        P, R, sc, sh, 12, H1a, P1a, t81, (long)NP1a * 96 / 8, t81, H1b, P1b, t82);
  }
  // ---- layer 2 (proven 128x128 kernel) ----
  {
    int BX1 = BX(NP2a), BXt = BX1 + BX(NP2b);
    dim3 g((unsigned)BXt, 2);
    conv_mfma<5, 4><<<g, 256, 0, stream>>>(R, W2, P, part, 96, 256, 256,
        P1a, H2a, NP2a, BX1, (long)NP(P1a) * 96, (long)NP2a * 256,
        P1b, H2b, NP2b);
    bn_finalize<<<512, 256, 0, stream>>>(part, bg[1], bb[1], sc, sh, 256, BX1, BXt,
                                         (float)NP2a, (float)NP2b);
    long t81 = (long)NP(P2a) * 256 / 8, t82 = (long)NP(P2b) * 256 / 8;
    bn_pool_k<<<(unsigned)((t81 + t82 + 255) / 256), 256, 0, stream>>>(
        P, R, sc, sh, 32, H2a, P2a, t81, (long)NP2a * 256 / 8, t81, H2b, P2b, t82);
  }
  // ---- layer 3 (96-co tiles, Co_pad 192) ----
  {
    int BX1 = BX(NP3a), BXt = BX1 + BX(NP3b);
    dim3 g((unsigned)BXt, 2);
    conv_mfma<3, 3><<<g, 256, 0, stream>>>(R, W3, P, part, 256, 192, 192,
        P2a, H3a, NP3a, BX1, (long)NP(P2a) * 256, (long)NP3a * 192,
        P2b, H3b, NP3b);
    bn_finalize<<<384, 256, 0, stream>>>(part, bg[2], bb[2], sc, sh, 192, BX1, BXt,
                                         (float)NP3a, (float)NP3b);
    long t81 = (long)NP3a * 192 / 8, t82 = (long)NP3b * 192 / 8;
    bn_apply_k<true, false><<<(unsigned)((t81 + t82 + 255) / 256), 256, 0, stream>>>(
        P, P, sc, sh, 192, t81, t82, t81, 0);
  }
  // ---- layer 4 (96-co tiles, Co_pad 192) ----
  {
    int BX1 = BX(NP4a), BXt = BX1 + BX(NP4b);
    dim3 g((unsigned)BXt, 2);
    conv_mfma<3, 3><<<g, 256, 0, stream>>>(P, W4, Q, part, 192, 192, 192,
        H3a, H4a, NP4a, BX1, (long)NP3a * 192, (long)NP4a * 192,
        H3b, H4b, NP4b);
    bn_finalize<<<384, 256, 0, stream>>>(part, bg[3], bb[3], sc, sh, 192, BX1, BXt,
                                         (float)NP4a, (float)NP4b);
    long t81 = (long)NP4a * 192 / 8, t82 = (long)NP4b * 192 / 8;
    bn_apply_k<true, false><<<(unsigned)((t81 + t82 + 255) / 256), 256, 0, stream>>>(
        Q, Q, sc, sh, 192, t81, t82, t81, 0);
  }
  // ---- layer 5 ----
  {
    int BX1 = BX(NP5a), BXt = BX1 + BX(NP5b);
    dim3 g((unsigned)BXt, 1);
    conv_mfma<3, 4><<<g, 256, 0, stream>>>(Q, W5, P, part, 192, 128, 128,
        H4a, H5a, NP5a, BX1, (long)NP4a * 192, (long)NP5a * 128,
        H4b, H5b, NP5b);
    bn_finalize<<<256, 256, 0, stream>>>(part, bg[4], bb[4], sc, sh, 128, BX1, BXt,
                                         (float)NP5a, (float)NP5b);
    long t81 = (long)NP5a * 128 / 8, t82 = (long)NP5b * 128 / 8;
    bn_apply_k<false, true><<<(unsigned)((t81 + t82 + 255) / 256), 256, 0, stream>>>(
        P, O12, sc, sh, 128, t81, t82, t81, (long)NP5a * 128 / 4);
  }

  xcorr_part<<<dim3(289, 32), 256, 0, stream>>>(O1, O2, part);
  xcorr_out<<<(9248 + 255) / 256, 256, 0, stream>>>(part, (float*)d_out, 9248);
}

// Round 15
// 515.711 us; speedup vs baseline: 1.2020x; 1.0677x over previous
//
#include <hip/hip_runtime.h>
#include <hip/hip_bf16.h>
#include <cstdint>
#include <cstddef>

typedef __attribute__((ext_vector_type(8))) _Float16 f16x8;
typedef __attribute__((ext_vector_type(4))) float f32x4;

__device__ __forceinline__ float h2f(unsigned short u) {
  union { unsigned short s; _Float16 h; } x; x.s = u; return (float)x.h;
}
__device__ __forceinline__ unsigned short f2h(float f) {
  union { unsigned short s; _Float16 h; } x; x.h = (_Float16)f; return x.s;
}
__device__ __forceinline__ void gload_lds16(const void* g, void* l) {
  __builtin_amdgcn_global_load_lds((const __attribute__((address_space(1))) unsigned int*)g,
                                   (__attribute__((address_space(3))) unsigned int*)l, 16, 0, 0);
}
// bijective XCD-aware block swizzle (m204): chunk logical blocks per XCD
__device__ __forceinline__ int xcd_swz(int bid, int nwg) {
  int q = nwg >> 3, r = nwg & 7;
  int x = bid & 7, idx = bid >> 3;
  return (x < r ? x * (q + 1) : r * (q + 1) + (x - r) * q) + idx;
}

// ============ merged input transform ============
__global__ void in_all(const float* __restrict__ in1, const float* __restrict__ in2,
                       unsigned short* __restrict__ o1, unsigned short* __restrict__ o2) {
  int i = blockIdx.x * 256 + threadIdx.x;
  const int p1 = 32 * 255 * 255;
  const int p2 = 32 * 127 * 127;
  const float* in;
  unsigned short* o;
  int HW;
  if (i < p1) {
    in = in1; o = o1; HW = 255 * 255;
  } else if (i < p1 + p2) {
    i -= p1; in = in2; o = o2; HW = 127 * 127;
  } else return;
  int n = i / HW;
  int r = i - n * HW;
  const float* p = in + (long)n * 3 * HW + r;
  uint2 v;
  v.x = (unsigned)f2h(p[0]) | ((unsigned)f2h(p[HW]) << 16);
  v.y = (unsigned)f2h(p[2 * HW]);
  ((uint2*)o)[i] = v;
}

// ============ merged weight transform ============
__device__ __forceinline__ void wtx(const float* __restrict__ w, unsigned short* __restrict__ o,
                                    long i, int Co, int Co_pad, int Ci, int KK) {
  int ci = (int)(i % Ci);
  long r = i / Ci;
  int co = (int)(r % Co_pad);
  int rk = (int)(r / Co_pad);
  float v = 0.f;
  if (co < Co) v = w[((long)co * Ci + ci) * KK + rk];
  o[i] = f2h(v);
}
__global__ void wt_all(const float* __restrict__ w1, const float* __restrict__ w2,
                       const float* __restrict__ w3, const float* __restrict__ w4,
                       const float* __restrict__ w5,
                       unsigned short* __restrict__ W1h, unsigned short* __restrict__ W2,
                       unsigned short* __restrict__ W3, unsigned short* __restrict__ W4,
                       unsigned short* __restrict__ W5) {
  long i = (long)blockIdx.x * 256 + threadIdx.x;
  const long t1 = 17 * 128 * 32;
  const long t2 = 25l * 256 * 96;
  const long t3 = 9l * 192 * 256;
  const long t4 = 9l * 192 * 192;
  const long t5 = 9l * 128 * 192;
  if (i < t1) {
    int j = (int)(i & 31);
    int r = (int)(i >> 5);
    int co = r & 127;
    int kk = r >> 7;
    int run = kk * 4 + (j >> 3);
    int ky = run / 6;
    int e = (run - ky * 6) * 8 + (j & 7);
    int kx = e >> 2, c = e & 3;
    float v = 0.f;
    if (ky < 11 && kx < 11 && c < 3 && co < 96)
      v = w1[((co * 3 + c) * 11 + ky) * 11 + kx];
    W1h[i] = f2h(v);
  } else if (i < t1 + t2) {
    wtx(w2, W2, i - t1, 256, 256, 96, 25);
  } else if (i < t1 + t2 + t3) {
    wtx(w3, W3, i - t1 - t2, 192, 192, 256, 9);
  } else if (i < t1 + t2 + t3 + t4) {
    wtx(w4, W4, i - t1 - t2 - t3, 192, 192, 192, 9);
  } else if (i < t1 + t2 + t3 + t4 + t5) {
    wtx(w5, W5, i - t1 - t2 - t3 - t4, 128, 128, 192, 9);
  }
}

// ============ conv1 MFMA: 128px x 96co (NB=3), dbuf + swizzle + fused stats ============
__global__ __launch_bounds__(256, 4)
void conv1_mfma(const unsigned short* __restrict__ in, const unsigned short* __restrict__ wt,
                unsigned short* __restrict__ out, float* __restrict__ part,
                int Hi1, int Ho1, int NPIX1, int BX1, long inOff2, long outOff2,
                int Hi2, int Ho2, int NPIX2) {
  __shared__ __align__(16) unsigned short sA[2][128 * 32];
  __shared__ __align__(16) unsigned short sB[2][128 * 32];
  __shared__ int sOB[128];
  __shared__ float sRed[4][48][2];
  const int t = threadIdx.x;
  const int bxg = xcd_swz(blockIdx.x, gridDim.x);
  const bool br2 = bxg >= BX1;
  const int lbx = br2 ? bxg - BX1 : bxg;
  const unsigned short* inB = in + (br2 ? inOff2 : 0);
  unsigned short* outB = out + (br2 ? outOff2 : 0);
  const int Hi = br2 ? Hi2 : Hi1, Wi = Hi;
  const int Ho = br2 ? Ho2 : Ho1, Wo = Ho;
  const int NPIX = br2 ? NPIX2 : NPIX1;
  const int px0 = lbx * 128;
  if (t < 128) {
    int g = px0 + t;
    int ob = -1;
    if (g < NPIX) {
      int n = g / (Ho * Wo);
      int r = g - n * Ho * Wo;
      int oy = r / Wo, ox = r - (r / Wo) * Wo;
      ob = ((n * Ho + oy) * Wo + ox) * 96;
    }
    sOB[t] = ob;
  }
  long rbase[2];
#pragma unroll
  for (int i = 0; i < 2; ++i) {
    int pxl = i * 64 + (t >> 2);
    int g = px0 + pxl;
    long rb = 0;
    if (g < NPIX) {
      int n = g / (Ho * Wo);
      int r = g - n * Ho * Wo;
      int oy = r / Wo, ox = r - (r / Wo) * Wo;
      rb = ((long)(n * Hi + 2 * oy) * Wi + 2 * ox) * 4;
    }
    rbase[i] = rb;
  }
  const int swz = (t & 3) ^ ((t >> 3) & 3);
  const int W4 = Wi * 4;
  f32x4 acc[4][3];
  f32x4 zz = {0.f, 0.f, 0.f, 0.f};
#pragma unroll
  for (int m = 0; m < 4; ++m)
#pragma unroll
    for (int n = 0; n < 3; ++n) acc[m][n] = zz;
  const int w = t >> 6;
  const int l = t & 63;
  const int wpx = (w & 1) * 64, wco = (w >> 1) * 48;
  const int arow = wpx + (l & 15);
  const int brow = wco + (l & 15);
  const int q8s = (((l >> 4) ^ (((l & 15) >> 1) & 3)) * 8);

  auto stage = [&](int buf, int kk) {
    int run = kk * 4 + swz;
    int ky = run / 6;
    int e0 = (run - ky * 6) * 8;
    long koff = (long)ky * W4 + e0;
    gload_lds16(inB + rbase[0] + koff, &sA[buf][t * 8]);
    gload_lds16(inB + rbase[1] + koff, &sA[buf][(256 + t) * 8]);
    const unsigned short* wp = wt + (long)kk * 4096;
    gload_lds16(wp + (t >> 2) * 32 + swz * 8, &sB[buf][t * 8]);
    if (t < 128)
      gload_lds16(wp + 2048 + (t >> 2) * 32 + swz * 8, &sB[buf][(256 + t) * 8]);
  };

  stage(0, 0);
  __syncthreads();
  int cur = 0;
#pragma unroll 1
  for (int kk = 0; kk < 17; ++kk) {
    if (kk + 1 < 17) stage(cur ^ 1, kk + 1);
    f16x8 av[4], bv[3];
#pragma unroll
    for (int m = 0; m < 4; ++m) av[m] = *(const f16x8*)&sA[cur][(arow + m * 16) * 32 + q8s];
#pragma unroll
    for (int n = 0; n < 3; ++n) bv[n] = *(const f16x8*)&sB[cur][(brow + n * 16) * 32 + q8s];
#pragma unroll
    for (int m = 0; m < 4; ++m)
#pragma unroll
      for (int n = 0; n < 3; ++n)
        acc[m][n] = __builtin_amdgcn_mfma_f32_16x16x32_f16(av[m], bv[n], acc[m][n], 0, 0, 0);
    __syncthreads();
    cur ^= 1;
  }
#pragma unroll
  for (int m = 0; m < 4; ++m) {
#pragma unroll
    for (int r = 0; r < 4; ++r) {
      int pxl = wpx + m * 16 + (l >> 4) * 4 + r;
      int ob = sOB[pxl];
#pragma unroll
      for (int n = 0; n < 3; ++n) {
        int co = wco + n * 16 + (l & 15);
        if (ob >= 0) outB[ob + co] = f2h(acc[m][n][r]);
      }
    }
  }
  float sn[3], qn[3];
#pragma unroll
  for (int n = 0; n < 3; ++n) { sn[n] = 0.f; qn[n] = 0.f; }
#pragma unroll
  for (int m = 0; m < 4; ++m) {
#pragma unroll
    for (int r = 0; r < 4; ++r) {
      int pxl = wpx + m * 16 + (l >> 4) * 4 + r;
      float msk = (px0 + pxl < NPIX) ? 1.f : 0.f;
#pragma unroll
      for (int n = 0; n < 3; ++n) {
        float v = acc[m][n][r] * msk;
        sn[n] += v;
        qn[n] = fmaf(v, v, qn[n]);
      }
    }
  }
#pragma unroll
  for (int n = 0; n < 3; ++n) {
    sn[n] += __shfl_xor(sn[n], 16, 64);
    sn[n] += __shfl_xor(sn[n], 32, 64);
    qn[n] += __shfl_xor(qn[n], 16, 64);
    qn[n] += __shfl_xor(qn[n], 32, 64);
  }
  if (l < 16) {
#pragma unroll
    for (int n = 0; n < 3; ++n) {
      sRed[w][n * 16 + l][0] = sn[n];
      sRed[w][n * 16 + l][1] = qn[n];
    }
  }
  __syncthreads();
  if (t < 96) {
    int g = t / 48;
    int cl = t - g * 48;
    float S = sRed[2 * g][cl][0] + sRed[2 * g + 1][cl][0];
    float Q = sRed[2 * g][cl][1] + sRed[2 * g + 1][cl][1];
    long idx = ((long)t * gridDim.x + bxg) * 2;
    part[idx] = S;
    part[idx + 1] = Q;
  }
}

// ============ implicit-GEMM MFMA conv: 128px x NB*32co per block ============
template <int K, int NB>
__global__ __launch_bounds__(256, 4)
void conv_mfma(const unsigned short* __restrict__ in, const unsigned short* __restrict__ wt,
               unsigned short* __restrict__ out, float* __restrict__ part,
               int Ci, int Co_pad, int Co_real,
               int Hi1, int Ho1, int NPIX1, int BX1, long inOff2, long outOff2,
               int Hi2, int Ho2, int NPIX2) {
  __shared__ __align__(16) unsigned short sA[2][128 * 32];
  __shared__ __align__(16) unsigned short sB[2][128 * 32];
  __shared__ int sOB[128];
  __shared__ float sRed[4][NB * 16][2];
  const int t = threadIdx.x;
  const int bxg = xcd_swz(blockIdx.x, gridDim.x);
  const bool br2 = bxg >= BX1;
  const int lbx = br2 ? bxg - BX1 : bxg;
  const unsigned short* inB = in + (br2 ? inOff2 : 0);
  unsigned short* outB = out + (br2 ? outOff2 : 0);
  const int Hi = br2 ? Hi2 : Hi1, Wi = Hi;
  const int Ho = br2 ? Ho2 : Ho1, Wo = Ho;
  const int NPIX = br2 ? NPIX2 : NPIX1;
  const int px0 = lbx * 128;
  const int co0 = blockIdx.y * (NB * 32);
  if (t < 128) {
    int g = px0 + t;
    int ob = -1;
    if (g < NPIX) {
      int n = g / (Ho * Wo);
      int r = g - n * Ho * Wo;
      int oy = r / Wo, ox = r - (r / Wo) * Wo;
      ob = ((n * Ho + oy) * Wo + ox) * Co_real;
    }
    sOB[t] = ob;
  }
  long rbase[2];
#pragma unroll
  for (int i = 0; i < 2; ++i) {
    int pxl = i * 64 + (t >> 2);
    int g = px0 + pxl;
    long rb = 0;
    if (g < NPIX) {
      int n = g / (Ho * Wo);
      int r = g - n * Ho * Wo;
      int oy = r / Wo, ox = r - (r / Wo) * Wo;
      rb = ((long)(n * Hi + oy) * Wi + ox) * Ci;
    }
    rbase[i] = rb;
  }
  const int seg8 = ((t & 3) ^ ((t >> 3) & 3)) * 8;
  const int colA = t >> 2;
  f32x4 acc[4][NB];
  f32x4 zz = {0.f, 0.f, 0.f, 0.f};
#pragma unroll
  for (int m = 0; m < 4; ++m)
#pragma unroll
    for (int n = 0; n < NB; ++n) acc[m][n] = zz;
  const int w = t >> 6;
  const int l = t & 63;
  const int wpx = (w & 1) * 64, wco = (w >> 1) * (NB * 16);
  const int arow = wpx + (l & 15);
  const int brow = wco + (l & 15);
  const int q8s = (((l >> 4) ^ (((l & 15) >> 1) & 3)) * 8);
  int ci0 = 0, kx = 0, ky = 0;
  const int NK = (Ci >> 5) * K * K;

  auto stage = [&](int buf) {
    long koff = (long)(ky * Wi + kx) * Ci + ci0 + seg8;
    gload_lds16(inB + rbase[0] + koff, &sA[buf][t * 8]);
    gload_lds16(inB + rbase[1] + koff, &sA[buf][(256 + t) * 8]);
    long wbase = (long)((ky * K + kx) * Co_pad + co0) * Ci + ci0 + seg8;
    gload_lds16(wt + wbase + (long)colA * Ci, &sB[buf][t * 8]);
    if (NB == 4 || t < 128)
      gload_lds16(wt + wbase + (long)(64 + colA) * Ci, &sB[buf][(256 + t) * 8]);
    ci0 += 32;
    if (ci0 == Ci) { ci0 = 0; ++kx; if (kx == K) { kx = 0; ++ky; } }
  };

  stage(0);
  __syncthreads();
  int cur = 0;
#pragma unroll 1
  for (int kk = 0; kk < NK; ++kk) {
    if (kk + 1 < NK) stage(cur ^ 1);
    f16x8 av[4], bv[NB];
#pragma unroll
    for (int m = 0; m < 4; ++m) av[m] = *(const f16x8*)&sA[cur][(arow + m * 16) * 32 + q8s];
#pragma unroll
    for (int n = 0; n < NB; ++n) bv[n] = *(const f16x8*)&sB[cur][(brow + n * 16) * 32 + q8s];
#pragma unroll
    for (int m = 0; m < 4; ++m)
#pragma unroll
      for (int n = 0; n < NB; ++n)
        acc[m][n] = __builtin_amdgcn_mfma_f32_16x16x32_f16(av[m], bv[n], acc[m][n], 0, 0, 0);
    __syncthreads();
    cur ^= 1;
  }
#pragma unroll
  for (int m = 0; m < 4; ++m) {
#pragma unroll
    for (int r = 0; r < 4; ++r) {
      int pxl = wpx + m * 16 + (l >> 4) * 4 + r;
      int ob = sOB[pxl];
#pragma unroll
      for (int n = 0; n < NB; ++n) {
        int co = co0 + wco + n * 16 + (l & 15);
        if (ob >= 0 && co < Co_real) outB[ob + co] = f2h(acc[m][n][r]);
      }
    }
  }
  float sn[NB], qn[NB];
#pragma unroll
  for (int n = 0; n < NB; ++n) { sn[n] = 0.f; qn[n] = 0.f; }
#pragma unroll
  for (int m = 0; m < 4; ++m) {
#pragma unroll
    for (int r = 0; r < 4; ++r) {
      int pxl = wpx + m * 16 + (l >> 4) * 4 + r;
      float msk = (px0 + pxl < NPIX) ? 1.f : 0.f;
#pragma unroll
      for (int n = 0; n < NB; ++n) {
        float v = acc[m][n][r] * msk;
        sn[n] += v;
        qn[n] = fmaf(v, v, qn[n]);
      }
    }
  }
#pragma unroll
  for (int n = 0; n < NB; ++n) {
    sn[n] += __shfl_xor(sn[n], 16, 64);
    sn[n] += __shfl_xor(sn[n], 32, 64);
    qn[n] += __shfl_xor(qn[n], 16, 64);
    qn[n] += __shfl_xor(qn[n], 32, 64);
  }
  if (l < 16) {
#pragma unroll
    for (int n = 0; n < NB; ++n) {
      sRed[w][n * 16 + l][0] = sn[n];
      sRed[w][n * 16 + l][1] = qn[n];
    }
  }
  __syncthreads();
  if (t < NB * 32) {
    int g = t / (NB * 16);
    int cl = t - g * (NB * 16);
    float S = sRed[2 * g][cl][0] + sRed[2 * g + 1][cl][0];
    float Q = sRed[2 * g][cl][1] + sRed[2 * g + 1][cl][1];
    long idx = ((long)(co0 + t) * gridDim.x + bxg) * 2;
    part[idx] = S;
    part[idx + 1] = Q;
  }
}

// ============ BN finalize, branch-merged ============
__global__ void bn_finalize(const float* __restrict__ part, const float* __restrict__ g,
                            const float* __restrict__ b, float* __restrict__ sc,
                            float* __restrict__ sh, int C, int BX1, int BXtot,
                            float cnt1, float cnt2) {
  const int cb = blockIdx.x;
  const bool br2 = cb >= C;
  const int c = br2 ? cb - C : cb;
  const int k0 = br2 ? BX1 : 0;
  const int k1 = br2 ? BXtot : BX1;
  const float cnt = br2 ? cnt2 : cnt1;
  const int t = threadIdx.x;
  float s = 0.f, q = 0.f;
  const float* pc = part + (long)c * BXtot * 2;
  for (int k = k0 + t; k < k1; k += 256) {
    s += pc[k * 2];
    q += pc[k * 2 + 1];
  }
  __shared__ float ss[256], qq[256];
  ss[t] = s; qq[t] = q;
  __syncthreads();
  for (int off = 128; off > 0; off >>= 1) {
    if (t < off) { ss[t] += ss[t + off]; qq[t] += qq[t + off]; }
    __syncthreads();
  }
  if (t == 0) {
    float m = ss[0] / cnt;
    float v = qq[0] / cnt - m * m;
    float r = rsqrtf(v + 1e-5f);
    float scl = r * g[c];
    int o = c + (br2 ? 256 : 0);
    sc[o] = scl;
    sh[o] = b[c] - m * scl;
  }
}

// ============ BN apply, branch-merged ============
template <bool RELU, bool OUTF32>
__global__ void bn_apply_k(const unsigned short* __restrict__ x, void* __restrict__ y,
                           const float* __restrict__ sc, const float* __restrict__ sh,
                           int C, long t81, long t82, long xOff2, long yOff2q4) {
  long i = (long)blockIdx.x * blockDim.x + threadIdx.x;
  if (i >= t81 + t82) return;
  const bool br2 = i >= t81;
  const long ii = br2 ? i - t81 : i;
  const int scO = br2 ? 256 : 0;
  const uint4 v = ((const uint4*)x + (br2 ? xOff2 : 0))[ii];
  int c0 = (int)((ii * 8) % C);
  const float4 s0 = *(const float4*)&sc[scO + c0];
  const float4 s1 = *(const float4*)&sc[scO + c0 + 4];
  const float4 h0 = *(const float4*)&sh[scO + c0];
  const float4 h1 = *(const float4*)&sh[scO + c0 + 4];
  float f[8];
  f[0] = h2f((unsigned short)(v.x & 0xffff)); f[1] = h2f((unsigned short)(v.x >> 16));
  f[2] = h2f((unsigned short)(v.y & 0xffff)); f[3] = h2f((unsigned short)(v.y >> 16));
  f[4] = h2f((unsigned short)(v.z & 0xffff)); f[5] = h2f((unsigned short)(v.z >> 16));
  f[6] = h2f((unsigned short)(v.w & 0xffff)); f[7] = h2f((unsigned short)(v.w >> 16));
  const float S[8] = {s0.x, s0.y, s0.z, s0.w, s1.x, s1.y, s1.z, s1.w};
  const float H[8] = {h0.x, h0.y, h0.z, h0.w, h1.x, h1.y, h1.z, h1.w};
#pragma unroll
  for (int j = 0; j < 8; ++j) {
    f[j] = fmaf(f[j], S[j], H[j]);
    if (RELU) f[j] = fmaxf(f[j], 0.f);
  }
  if (OUTF32) {
    float4* yb = (float4*)y + (br2 ? yOff2q4 : 0);
    float4 o0 = {f[0], f[1], f[2], f[3]}, o1 = {f[4], f[5], f[6], f[7]};
    yb[2 * ii] = o0;
    yb[2 * ii + 1] = o1;
  } else {
    uint4 o;
    o.x = (unsigned)f2h(f[0]) | ((unsigned)f2h(f[1]) << 16);
    o.y = (unsigned)f2h(f[2]) | ((unsigned)f2h(f[3]) << 16);
    o.z = (unsigned)f2h(f[4]) | ((unsigned)f2h(f[5]) << 16);
    o.w = (unsigned)f2h(f[6]) | ((unsigned)f2h(f[7]) << 16);
    ((uint4*)y + (br2 ? xOff2 : 0))[ii] = o;
  }
}

// ============ fused BN+ReLU+MaxPool 3x3 s2, branch-merged ============
__global__ void bn_pool_k(const unsigned short* __restrict__ in, unsigned short* __restrict__ out,
                          const float* __restrict__ sc, const float* __restrict__ sh,
                          int C8, int Hi1, int Ho1, long t81, long inOff2, long outOff2,
                          int Hi2, int Ho2, long t82) {
  long i = (long)blockIdx.x * blockDim.x + threadIdx.x;
  if (i >= t81 + t82) return;
  const bool br2 = i >= t81;
  const long ii = br2 ? i - t81 : i;
  const int Hi = br2 ? Hi2 : Hi1, Wi = Hi;
  const int Ho = br2 ? Ho2 : Ho1, Wo = Ho;
  const int scO = br2 ? 256 : 0;
  const uint4* inB = (const uint4*)in + (br2 ? inOff2 : 0);
  uint4* outB = (uint4*)out + (br2 ? outOff2 : 0);
  int cg = (int)(ii % C8);
  long r = ii / C8;
  int ox = (int)(r % Wo);
  r /= Wo;
  int oy = (int)(r % Ho);
  int n = (int)(r / Ho);
  const int c0 = cg * 8;
  const float4 s0 = *(const float4*)&sc[scO + c0];
  const float4 s1 = *(const float4*)&sc[scO + c0 + 4];
  const float4 h0 = *(const float4*)&sh[scO + c0];
  const float4 h1 = *(const float4*)&sh[scO + c0 + 4];
  const float S[8] = {s0.x, s0.y, s0.z, s0.w, s1.x, s1.y, s1.z, s1.w};
  const float H[8] = {h0.x, h0.y, h0.z, h0.w, h1.x, h1.y, h1.z, h1.w};
  const uint4* bp = inB + ((long)(n * Hi + 2 * oy) * Wi + 2 * ox) * C8 + cg;
  float m[8];
#pragma unroll
  for (int j = 0; j < 8; ++j) m[j] = -3.4e38f;
#pragma unroll
  for (int dy = 0; dy < 3; ++dy)
#pragma unroll
    for (int dx = 0; dx < 3; ++dx) {
      const uint4 v = bp[((long)dy * Wi + dx) * C8];
      float f[8];
      f[0] = h2f((unsigned short)(v.x & 0xffff)); f[1] = h2f((unsigned short)(v.x >> 16));
      f[2] = h2f((unsigned short)(v.y & 0xffff)); f[3] = h2f((unsigned short)(v.y >> 16));
      f[4] = h2f((unsigned short)(v.z & 0xffff)); f[5] = h2f((unsigned short)(v.z >> 16));
      f[6] = h2f((unsigned short)(v.w & 0xffff)); f[7] = h2f((unsigned short)(v.w >> 16));
#pragma unroll
      for (int j = 0; j < 8; ++j) {
        f[j] = fmaxf(fmaf(f[j], S[j], H[j]), 0.f);
        m[j] = fmaxf(m[j], f[j]);
      }
    }
  uint4 o;
  o.x = (unsigned)f2h(m[0]) | ((unsigned)f2h(m[1]) << 16);
  o.y = (unsigned)f2h(m[2]) | ((unsigned)f2h(m[3]) << 16);
  o.z = (unsigned)f2h(m[4]) | ((unsigned)f2h(m[5]) << 16);
  o.w = (unsigned)f2h(m[6]) | ((unsigned)f2h(m[7]) << 16);
  outB[ii] = o;
}

// ============ cross-correlation ============
__global__ void xcorr_part(const float* __restrict__ o1, const float* __restrict__ o2,
                           float* __restrict__ part) {
  const int p = blockIdx.x;
  const int b = blockIdx.y;
  const int oy = p / 17, ox = p - (p / 17) * 17;
  const float* o1b = o1 + (long)b * 22 * 22 * 128;
  const float* o2b = o2 + (long)b * 4608;
  float acc = 0.f;
  for (int i = threadIdx.x; i < 4608; i += 256) {
    int c = i & 127;
    int r = i >> 7;
    int kx = r % 6, ky = r / 6;
    acc = fmaf(o1b[((oy + ky) * 22 + ox + kx) * 128 + c], o2b[i], acc);
  }
#pragma unroll
  for (int off = 32; off > 0; off >>= 1) acc += __shfl_down(acc, off, 64);
  __shared__ float sh[4];
  const int lane = threadIdx.x & 63, wid = threadIdx.x >> 6;
  if (lane == 0) sh[wid] = acc;
  __syncthreads();
  if (threadIdx.x == 0) part[p * 32 + b] = sh[0] + sh[1] + sh[2] + sh[3];
}

__global__ void xcorr_out(const float* __restrict__ part, float* __restrict__ out, int total) {
  int i = blockIdx.x * 256 + threadIdx.x;
  if (i >= total) return;
  int p = i % 289;
  float s = 0.f;
  for (int b = 0; b < 32; ++b) s += part[p * 32 + b];
  out[i] = s * (1.f / 147456.f);
}

// ============ host ============
extern "C" void kernel_launch(void* const* d_in, const int* in_sizes, int n_in,
                              void* d_out, int out_size, void* d_ws, size_t ws_size,
                              hipStream_t stream) {
  (void)in_sizes; (void)n_in; (void)ws_size; (void)out_size;
  const float* input1 = (const float*)d_in[0];
  const float* input2 = (const float*)d_in[1];
  const float* cw[5];
  const float* bg[5];
  const float* bb[5];
  for (int i = 0; i < 5; ++i) {
    cw[i] = (const float*)d_in[2 + 2 * i];
    bg[i] = (const float*)d_in[12 + 2 * i];
    bb[i] = (const float*)d_in[13 + 2 * i];
  }
  const int H1a = 123, P1a = 61, H2a = 57, P2a = 28, H3a = 26, H4a = 24, H5a = 22;
  const int H1b = 59, P1b = 29, H2b = 25, P2b = 12, H3b = 10, H4b = 8, H5b = 6;
  auto NP = [](int h) { return 32 * h * h; };
  const int NP1a = NP(H1a), NP1b = NP(H1b);
  const int NP2a = NP(H2a), NP2b = NP(H2b);
  const int NP3a = NP(H3a), NP3b = NP(H3b);
  const int NP4a = NP(H4a), NP4b = NP(H4b);
  const int NP5a = NP(H5a), NP5b = NP(H5b);
  auto BX = [](int np) { return (np + 127) / 128; };

  char* p = (char*)d_ws;
  auto alloc = [&](size_t bytes) {
    char* r = p;
    p += (bytes + 255) & ~(size_t)255;
    return r;
  };
  unsigned short* P = (unsigned short*)alloc(((size_t)NP1a + NP1b) * 96 * 2);
  unsigned short* R = (unsigned short*)alloc(((size_t)NP(P1a) + NP(P1b)) * 96 * 2 + 262144);
  unsigned short* Q = (unsigned short*)alloc(((size_t)NP4a + NP4b) * 192 * 2);
  float* O12 = (float*)alloc(((size_t)NP5a + NP5b) * 128 * 4);
  unsigned short* I12h = (unsigned short*)alloc(((size_t)32 * 255 * 255 * 4 + (size_t)32 * 127 * 127 * 4) * 2 + 65536);
  unsigned short* W1h = (unsigned short*)alloc(17l * 128 * 32 * 2);
  unsigned short* W2 = (unsigned short*)alloc(25l * 256 * 96 * 2);
  unsigned short* W3 = (unsigned short*)alloc(9l * 192 * 256 * 2);
  unsigned short* W4 = (unsigned short*)alloc(9l * 192 * 192 * 2);
  unsigned short* W5 = (unsigned short*)alloc(9l * 128 * 192 * 2);
  float* part = (float*)alloc(9000000);
  float* sc = (float*)alloc(512 * 4);
  float* sh = (float*)alloc(512 * 4);
  float* O1 = O12;
  float* O2 = O12 + (size_t)NP5a * 128;

  {
    long wt_tot = 17l * 128 * 32 + 25l * 256 * 96 + 9l * 192 * 256 + 9l * 192 * 192 + 9l * 128 * 192;
    wt_all<<<(unsigned)((wt_tot + 255) / 256), 256, 0, stream>>>(cw[0], cw[1], cw[2], cw[3], cw[4],
                                                                 W1h, W2, W3, W4, W5);
    long in_tot = 32l * 255 * 255 + 32l * 127 * 127;
    in_all<<<(unsigned)((in_tot + 255) / 256), 256, 0, stream>>>(input1, input2, I12h,
                                                                 I12h + 32l * 255 * 255 * 4);
  }

  // ---- layer 1 (96-co tiles) ----
  {
    int BX1 = BX(NP1a), BXt = BX1 + BX(NP1b);
    conv1_mfma<<<(unsigned)BXt, 256, 0, stream>>>(I12h, W1h, P, part,
        255, H1a, NP1a, BX1, 32l * 255 * 255 * 4, (long)NP1a * 96,
        127, H1b, NP1b);
    bn_finalize<<<192, 256, 0, stream>>>(part, bg[0], bb[0], sc, sh, 96, BX1, BXt,
                                         (float)NP1a, (float)NP1b);
    long t81 = (long)NP(P1a) * 96 / 8, t82 = (long)NP(P1b) * 96 / 8;
    bn_pool_k<<<(unsigned)((t81 + t82 + 255) / 256), 256, 0, stream>>>(
        P, R, sc, sh, 12, H1a, P1a, t81, (long)NP1a * 96 / 8, t81, H1b, P1b, t82);
  }
  // ---- layer 2 ----
  {
    int BX1 = BX(NP2a), BXt = BX1 + BX(NP2b);
    dim3 g((unsigned)BXt, 2);
    conv_mfma<5, 4><<<g, 256, 0, stream>>>(R, W2, P, part, 96, 256, 256,
        P1a, H2a, NP2a, BX1, (long)NP(P1a) * 96, (long)NP2a * 256,
        P1b, H2b, NP2b);
    bn_finalize<<<512, 256, 0, stream>>>(part, bg[1], bb[1], sc, sh, 256, BX1, BXt,
                                         (float)NP2a, (float)NP2b);
    long t81 = (long)NP(P2a) * 256 / 8, t82 = (long)NP(P2b) * 256 / 8;
    bn_pool_k<<<(unsigned)((t81 + t82 + 255) / 256), 256, 0, stream>>>(
        P, R, sc, sh, 32, H2a, P2a, t81, (long)NP2a * 256 / 8, t81, H2b, P2b, t82);
  }
  // ---- layer 3 (96-co tiles, Co_pad 192) ----
  {
    int BX1 = BX(NP3a), BXt = BX1 + BX(NP3b);
    dim3 g((unsigned)BXt, 2);
    conv_mfma<3, 3><<<g, 256, 0, stream>>>(R, W3, P, part, 256, 192, 192,
        P2a, H3a, NP3a, BX1, (long)NP(P2a) * 256, (long)NP3a * 192,
        P2b, H3b, NP3b);
    bn_finalize<<<384, 256, 0, stream>>>(part, bg[2], bb[2], sc, sh, 192, BX1, BXt,
                                         (float)NP3a, (float)NP3b);
    long t81 = (long)NP3a * 192 / 8, t82 = (long)NP3b * 192 / 8;
    bn_apply_k<true, false><<<(unsigned)((t81 + t82 + 255) / 256), 256, 0, stream>>>(
        P, P, sc, sh, 192, t81, t82, t81, 0);
  }
  // ---- layer 4 (96-co tiles, Co_pad 192) ----
  {
    int BX1 = BX(NP4a), BXt = BX1 + BX(NP4b);
    dim3 g((unsigned)BXt, 2);
    conv_mfma<3, 3><<<g, 256, 0, stream>>>(P, W4, Q, part, 192, 192, 192,
        H3a, H4a, NP4a, BX1, (long)NP3a * 192, (long)NP4a * 192,
        H3b, H4b, NP4b);
    bn_finalize<<<384, 256, 0, stream>>>(part, bg[3], bb[3], sc, sh, 192, BX1, BXt,
                                         (float)NP4a, (float)NP4b);
    long t81 = (long)NP4a * 192 / 8, t82 = (long)NP4b * 192 / 8;
    bn_apply_k<true, false><<<(unsigned)((t81 + t82 + 255) / 256), 256, 0, stream>>>(
        Q, Q, sc, sh, 192, t81, t82, t81, 0);
  }
  // ---- layer 5 ----
  {
    int BX1 = BX(NP5a), BXt = BX1 + BX(NP5b);
    dim3 g((unsigned)BXt, 1);
    conv_mfma<3, 4><<<g, 256, 0, stream>>>(Q, W5, P, part, 192, 128, 128,
        H4a, H5a, NP5a, BX1, (long)NP4a * 192, (long)NP5a * 128,
        H4b, H5b, NP5b);
    bn_finalize<<<256, 256, 0, stream>>>(part, bg[4], bb[4], sc, sh, 128, BX1, BXt,
                                         (float)NP5a, (float)NP5b);
    long t81 = (long)NP5a * 128 / 8, t82 = (long)NP5b * 128 / 8;
    bn_apply_k<false, true><<<(unsigned)((t81 + t82 + 255) / 256), 256, 0, stream>>>(
        P, O12, sc, sh, 128, t81, t82, t81, (long)NP5a * 128 / 4);
  }

  xcorr_part<<<dim3(289, 32), 256, 0, stream>>>(O1, O2, part);
  xcorr_out<<<(9248 + 255) / 256, 256, 0, stream>>>(part, (float*)d_out, 9248);
}

// Round 16
// 507.581 us; speedup vs baseline: 1.2213x; 1.0160x over previous
//
#include <hip/hip_runtime.h>
#include <hip/hip_bf16.h>
#include <cstdint>
#include <cstddef>

typedef __attribute__((ext_vector_type(8))) _Float16 f16x8;
typedef __attribute__((ext_vector_type(4))) float f32x4;

__device__ __forceinline__ float h2f(unsigned short u) {
  union { unsigned short s; _Float16 h; } x; x.s = u; return (float)x.h;
}
__device__ __forceinline__ unsigned short f2h(float f) {
  union { unsigned short s; _Float16 h; } x; x.h = (_Float16)f; return x.s;
}
__device__ __forceinline__ void gload_lds16(const void* g, void* l) {
  __builtin_amdgcn_global_load_lds((const __attribute__((address_space(1))) unsigned int*)g,
                                   (__attribute__((address_space(3))) unsigned int*)l, 16, 0, 0);
}
// bijective XCD-aware block swizzle (m204)
__device__ __forceinline__ int xcd_swz(int bid, int nwg) {
  int q = nwg >> 3, r = nwg & 7;
  int x = bid & 7, idx = bid >> 3;
  return (x < r ? x * (q + 1) : r * (q + 1) + (x - r) * q) + idx;
}

// ============ merged prep: input transforms + all weight transforms ============
__device__ __forceinline__ void wtx(const float* __restrict__ w, unsigned short* __restrict__ o,
                                    long i, int Co, int Co_pad, int Ci, int KK) {
  int ci = (int)(i % Ci);
  long r = i / Ci;
  int co = (int)(r % Co_pad);
  int rk = (int)(r / Co_pad);
  float v = 0.f;
  if (co < Co) v = w[((long)co * Ci + ci) * KK + rk];
  o[i] = f2h(v);
}
__global__ void prep_all(const float* __restrict__ in1, const float* __restrict__ in2,
                         unsigned short* __restrict__ o1, unsigned short* __restrict__ o2,
                         const float* __restrict__ w1, const float* __restrict__ w2,
                         const float* __restrict__ w3, const float* __restrict__ w4,
                         const float* __restrict__ w5,
                         unsigned short* __restrict__ W1h, unsigned short* __restrict__ W2,
                         unsigned short* __restrict__ W3, unsigned short* __restrict__ W4,
                         unsigned short* __restrict__ W5) {
  long gi = (long)blockIdx.x * 256 + threadIdx.x;
  const long p1 = 32l * 255 * 255;
  const long p2 = 32l * 127 * 127;
  if (gi < p1 + p2) {
    const float* in;
    unsigned short* o;
    int HW;
    long i = gi;
    if (i < p1) {
      in = in1; o = o1; HW = 255 * 255;
    } else {
      i -= p1; in = in2; o = o2; HW = 127 * 127;
    }
    int n = (int)(i / HW);
    int r = (int)(i - (long)n * HW);
    const float* p = in + (long)n * 3 * HW + r;
    uint2 v;
    v.x = (unsigned)f2h(p[0]) | ((unsigned)f2h(p[HW]) << 16);
    v.y = (unsigned)f2h(p[2 * HW]);
    ((uint2*)o)[i] = v;
    return;
  }
  long i = gi - (p1 + p2);
  const long t1 = 17 * 128 * 32;
  const long t2 = 25l * 256 * 96;
  const long t3 = 9l * 192 * 256;
  const long t4 = 9l * 192 * 192;
  const long t5 = 9l * 128 * 192;
  if (i < t1) {
    int j = (int)(i & 31);
    int r = (int)(i >> 5);
    int co = r & 127;
    int kk = r >> 7;
    int run = kk * 4 + (j >> 3);
    int ky = run / 6;
    int e = (run - ky * 6) * 8 + (j & 7);
    int kx = e >> 2, c = e & 3;
    float v = 0.f;
    if (ky < 11 && kx < 11 && c < 3 && co < 96)
      v = w1[((co * 3 + c) * 11 + ky) * 11 + kx];
    W1h[i] = f2h(v);
  } else if (i < t1 + t2) {
    wtx(w2, W2, i - t1, 256, 256, 96, 25);
  } else if (i < t1 + t2 + t3) {
    wtx(w3, W3, i - t1 - t2, 192, 192, 256, 9);
  } else if (i < t1 + t2 + t3 + t4) {
    wtx(w4, W4, i - t1 - t2 - t3, 192, 192, 192, 9);
  } else if (i < t1 + t2 + t3 + t4 + t5) {
    wtx(w5, W5, i - t1 - t2 - t3 - t4, 128, 128, 192, 9);
  }
}

// ============ conv1 MFMA: 128px x 96co (NB=3), dbuf + swizzle + fused stats ============
__global__ __launch_bounds__(256, 4)
void conv1_mfma(const unsigned short* __restrict__ in, const unsigned short* __restrict__ wt,
                unsigned short* __restrict__ out, float* __restrict__ part,
                int Hi1, int Ho1, int NPIX1, int BX1, long inOff2, long outOff2,
                int Hi2, int Ho2, int NPIX2) {
  __shared__ __align__(16) unsigned short sA[2][128 * 32];
  __shared__ __align__(16) unsigned short sB[2][128 * 32];
  __shared__ int sOB[128];
  __shared__ float sRed[4][48][2];
  const int t = threadIdx.x;
  const int bxg = xcd_swz(blockIdx.x, gridDim.x);
  const bool br2 = bxg >= BX1;
  const int lbx = br2 ? bxg - BX1 : bxg;
  const unsigned short* inB = in + (br2 ? inOff2 : 0);
  unsigned short* outB = out + (br2 ? outOff2 : 0);
  const int Hi = br2 ? Hi2 : Hi1, Wi = Hi;
  const int Ho = br2 ? Ho2 : Ho1, Wo = Ho;
  const int NPIX = br2 ? NPIX2 : NPIX1;
  const int px0 = lbx * 128;
  if (t < 128) {
    int g = px0 + t;
    int ob = -1;
    if (g < NPIX) {
      int n = g / (Ho * Wo);
      int r = g - n * Ho * Wo;
      int oy = r / Wo, ox = r - (r / Wo) * Wo;
      ob = ((n * Ho + oy) * Wo + ox) * 96;
    }
    sOB[t] = ob;
  }
  long rbase[2];
#pragma unroll
  for (int i = 0; i < 2; ++i) {
    int pxl = i * 64 + (t >> 2);
    int g = px0 + pxl;
    long rb = 0;
    if (g < NPIX) {
      int n = g / (Ho * Wo);
      int r = g - n * Ho * Wo;
      int oy = r / Wo, ox = r - (r / Wo) * Wo;
      rb = ((long)(n * Hi + 2 * oy) * Wi + 2 * ox) * 4;
    }
    rbase[i] = rb;
  }
  const int swz = (t & 3) ^ ((t >> 3) & 3);
  const int W4 = Wi * 4;
  f32x4 acc[4][3];
  f32x4 zz = {0.f, 0.f, 0.f, 0.f};
#pragma unroll
  for (int m = 0; m < 4; ++m)
#pragma unroll
    for (int n = 0; n < 3; ++n) acc[m][n] = zz;
  const int w = t >> 6;
  const int l = t & 63;
  const int wpx = (w & 1) * 64, wco = (w >> 1) * 48;
  const int arow = wpx + (l & 15);
  const int brow = wco + (l & 15);
  const int q8s = (((l >> 4) ^ (((l & 15) >> 1) & 3)) * 8);

  auto stage = [&](int buf, int kk) {
    int run = kk * 4 + swz;
    int ky = run / 6;
    int e0 = (run - ky * 6) * 8;
    long koff = (long)ky * W4 + e0;
    gload_lds16(inB + rbase[0] + koff, &sA[buf][t * 8]);
    gload_lds16(inB + rbase[1] + koff, &sA[buf][(256 + t) * 8]);
    const unsigned short* wp = wt + (long)kk * 4096;
    gload_lds16(wp + (t >> 2) * 32 + swz * 8, &sB[buf][t * 8]);
    if (t < 128)
      gload_lds16(wp + 2048 + (t >> 2) * 32 + swz * 8, &sB[buf][(256 + t) * 8]);
  };

  stage(0, 0);
  __syncthreads();
  int cur = 0;
#pragma unroll 1
  for (int kk = 0; kk < 17; ++kk) {
    if (kk + 1 < 17) stage(cur ^ 1, kk + 1);
    f16x8 av[4], bv[3];
#pragma unroll
    for (int m = 0; m < 4; ++m) av[m] = *(const f16x8*)&sA[cur][(arow + m * 16) * 32 + q8s];
#pragma unroll
    for (int n = 0; n < 3; ++n) bv[n] = *(const f16x8*)&sB[cur][(brow + n * 16) * 32 + q8s];
#pragma unroll
    for (int m = 0; m < 4; ++m)
#pragma unroll
      for (int n = 0; n < 3; ++n)
        acc[m][n] = __builtin_amdgcn_mfma_f32_16x16x32_f16(av[m], bv[n], acc[m][n], 0, 0, 0);
    __syncthreads();
    cur ^= 1;
  }
#pragma unroll
  for (int m = 0; m < 4; ++m) {
#pragma unroll
    for (int r = 0; r < 4; ++r) {
      int pxl = wpx + m * 16 + (l >> 4) * 4 + r;
      int ob = sOB[pxl];
#pragma unroll
      for (int n = 0; n < 3; ++n) {
        int co = wco + n * 16 + (l & 15);
        if (ob >= 0) outB[ob + co] = f2h(acc[m][n][r]);
      }
    }
  }
  float sn[3], qn[3];
#pragma unroll
  for (int n = 0; n < 3; ++n) { sn[n] = 0.f; qn[n] = 0.f; }
#pragma unroll
  for (int m = 0; m < 4; ++m) {
#pragma unroll
    for (int r = 0; r < 4; ++r) {
      int pxl = wpx + m * 16 + (l >> 4) * 4 + r;
      float msk = (px0 + pxl < NPIX) ? 1.f : 0.f;
#pragma unroll
      for (int n = 0; n < 3; ++n) {
        float v = acc[m][n][r] * msk;
        sn[n] += v;
        qn[n] = fmaf(v, v, qn[n]);
      }
    }
  }
#pragma unroll
  for (int n = 0; n < 3; ++n) {
    sn[n] += __shfl_xor(sn[n], 16, 64);
    sn[n] += __shfl_xor(sn[n], 32, 64);
    qn[n] += __shfl_xor(qn[n], 16, 64);
    qn[n] += __shfl_xor(qn[n], 32, 64);
  }
  if (l < 16) {
#pragma unroll
    for (int n = 0; n < 3; ++n) {
      sRed[w][n * 16 + l][0] = sn[n];
      sRed[w][n * 16 + l][1] = qn[n];
    }
  }
  __syncthreads();
  if (t < 96) {
    int g = t / 48;
    int cl = t - g * 48;
    float S = sRed[2 * g][cl][0] + sRed[2 * g + 1][cl][0];
    float Q = sRed[2 * g][cl][1] + sRed[2 * g + 1][cl][1];
    long idx = ((long)t * gridDim.x + bxg) * 2;
    part[idx] = S;
    part[idx + 1] = Q;
  }
}

// ============ implicit-GEMM MFMA conv: 128px x NB*32co, 1D grid (co fast) ============
template <int K, int NB, int NCO>
__global__ __launch_bounds__(256, 4)
void conv_mfma(const unsigned short* __restrict__ in, const unsigned short* __restrict__ wt,
               unsigned short* __restrict__ out, float* __restrict__ part,
               int Ci, int Co_pad, int Co_real,
               int Hi1, int Ho1, int NPIX1, int BX1, long inOff2, long outOff2,
               int Hi2, int Ho2, int NPIX2) {
  __shared__ __align__(16) unsigned short sA[2][128 * 32];
  __shared__ __align__(16) unsigned short sB[2][128 * 32];
  __shared__ int sOB[128];
  __shared__ float sRed[4][NB * 16][2];
  const int t = threadIdx.x;
  const int nT = gridDim.x / NCO;        // px-tile count (= BXt)
  int tile, coid;
  if (NCO == 2) { tile = blockIdx.x >> 1; coid = blockIdx.x & 1; }
  else { tile = blockIdx.x; coid = 0; }
  const int bxg = xcd_swz(tile, nT);
  const bool br2 = bxg >= BX1;
  const int lbx = br2 ? bxg - BX1 : bxg;
  const unsigned short* inB = in + (br2 ? inOff2 : 0);
  unsigned short* outB = out + (br2 ? outOff2 : 0);
  const int Hi = br2 ? Hi2 : Hi1, Wi = Hi;
  const int Ho = br2 ? Ho2 : Ho1, Wo = Ho;
  const int NPIX = br2 ? NPIX2 : NPIX1;
  const int px0 = lbx * 128;
  const int co0 = coid * (NB * 32);
  if (t < 128) {
    int g = px0 + t;
    int ob = -1;
    if (g < NPIX) {
      int n = g / (Ho * Wo);
      int r = g - n * Ho * Wo;
      int oy = r / Wo, ox = r - (r / Wo) * Wo;
      ob = ((n * Ho + oy) * Wo + ox) * Co_real;
    }
    sOB[t] = ob;
  }
  long rbase[2];
#pragma unroll
  for (int i = 0; i < 2; ++i) {
    int pxl = i * 64 + (t >> 2);
    int g = px0 + pxl;
    long rb = 0;
    if (g < NPIX) {
      int n = g / (Ho * Wo);
      int r = g - n * Ho * Wo;
      int oy = r / Wo, ox = r - (r / Wo) * Wo;
      rb = ((long)(n * Hi + oy) * Wi + ox) * Ci;
    }
    rbase[i] = rb;
  }
  const int seg8 = ((t & 3) ^ ((t >> 3) & 3)) * 8;
  const int colA = t >> 2;
  f32x4 acc[4][NB];
  f32x4 zz = {0.f, 0.f, 0.f, 0.f};
#pragma unroll
  for (int m = 0; m < 4; ++m)
#pragma unroll
    for (int n = 0; n < NB; ++n) acc[m][n] = zz;
  const int w = t >> 6;
  const int l = t & 63;
  const int wpx = (w & 1) * 64, wco = (w >> 1) * (NB * 16);
  const int arow = wpx + (l & 15);
  const int brow = wco + (l & 15);
  const int q8s = (((l >> 4) ^ (((l & 15) >> 1) & 3)) * 8);
  int ci0 = 0, kx = 0, ky = 0;
  const int NK = (Ci >> 5) * K * K;

  auto stage = [&](int buf) {
    long koff = (long)(ky * Wi + kx) * Ci + ci0 + seg8;
    gload_lds16(inB + rbase[0] + koff, &sA[buf][t * 8]);
    gload_lds16(inB + rbase[1] + koff, &sA[buf][(256 + t) * 8]);
    long wbase = (long)((ky * K + kx) * Co_pad + co0) * Ci + ci0 + seg8;
    gload_lds16(wt + wbase + (long)colA * Ci, &sB[buf][t * 8]);
    if (NB == 4 || t < 128)
      gload_lds16(wt + wbase + (long)(64 + colA) * Ci, &sB[buf][(256 + t) * 8]);
    ci0 += 32;
    if (ci0 == Ci) { ci0 = 0; ++kx; if (kx == K) { kx = 0; ++ky; } }
  };

  stage(0);
  __syncthreads();
  int cur = 0;
#pragma unroll 1
  for (int kk = 0; kk < NK; ++kk) {
    if (kk + 1 < NK) stage(cur ^ 1);
    f16x8 av[4], bv[NB];
#pragma unroll
    for (int m = 0; m < 4; ++m) av[m] = *(const f16x8*)&sA[cur][(arow + m * 16) * 32 + q8s];
#pragma unroll
    for (int n = 0; n < NB; ++n) bv[n] = *(const f16x8*)&sB[cur][(brow + n * 16) * 32 + q8s];
#pragma unroll
    for (int m = 0; m < 4; ++m)
#pragma unroll
      for (int n = 0; n < NB; ++n)
        acc[m][n] = __builtin_amdgcn_mfma_f32_16x16x32_f16(av[m], bv[n], acc[m][n], 0, 0, 0);
    __syncthreads();
    cur ^= 1;
  }
#pragma unroll
  for (int m = 0; m < 4; ++m) {
#pragma unroll
    for (int r = 0; r < 4; ++r) {
      int pxl = wpx + m * 16 + (l >> 4) * 4 + r;
      int ob = sOB[pxl];
#pragma unroll
      for (int n = 0; n < NB; ++n) {
        int co = co0 + wco + n * 16 + (l & 15);
        if (ob >= 0 && co < Co_real) outB[ob + co] = f2h(acc[m][n][r]);
      }
    }
  }
  float sn[NB], qn[NB];
#pragma unroll
  for (int n = 0; n < NB; ++n) { sn[n] = 0.f; qn[n] = 0.f; }
#pragma unroll
  for (int m = 0; m < 4; ++m) {
#pragma unroll
    for (int r = 0; r < 4; ++r) {
      int pxl = wpx + m * 16 + (l >> 4) * 4 + r;
      float msk = (px0 + pxl < NPIX) ? 1.f : 0.f;
#pragma unroll
      for (int n = 0; n < NB; ++n) {
        float v = acc[m][n][r] * msk;
        sn[n] += v;
        qn[n] = fmaf(v, v, qn[n]);
      }
    }
  }
#pragma unroll
  for (int n = 0; n < NB; ++n) {
    sn[n] += __shfl_xor(sn[n], 16, 64);
    sn[n] += __shfl_xor(sn[n], 32, 64);
    qn[n] += __shfl_xor(qn[n], 16, 64);
    qn[n] += __shfl_xor(qn[n], 32, 64);
  }
  if (l < 16) {
#pragma unroll
    for (int n = 0; n < NB; ++n) {
      sRed[w][n * 16 + l][0] = sn[n];
      sRed[w][n * 16 + l][1] = qn[n];
    }
  }
  __syncthreads();
  if (t < NB * 32) {
    int g = t / (NB * 16);
    int cl = t - g * (NB * 16);
    float S = sRed[2 * g][cl][0] + sRed[2 * g + 1][cl][0];
    float Q = sRed[2 * g][cl][1] + sRed[2 * g + 1][cl][1];
    long idx = ((long)(co0 + t) * nT + bxg) * 2;
    part[idx] = S;
    part[idx + 1] = Q;
  }
}

// ============ BN finalize, branch-merged ============
__global__ void bn_finalize(const float* __restrict__ part, const float* __restrict__ g,
                            const float* __restrict__ b, float* __restrict__ sc,
                            float* __restrict__ sh, int C, int BX1, int BXtot,
                            float cnt1, float cnt2) {
  const int cb = blockIdx.x;
  const bool br2 = cb >= C;
  const int c = br2 ? cb - C : cb;
  const int k0 = br2 ? BX1 : 0;
  const int k1 = br2 ? BXtot : BX1;
  const float cnt = br2 ? cnt2 : cnt1;
  const int t = threadIdx.x;
  float s = 0.f, q = 0.f;
  const float* pc = part + (long)c * BXtot * 2;
  for (int k = k0 + t; k < k1; k += 256) {
    s += pc[k * 2];
    q += pc[k * 2 + 1];
  }
  __shared__ float ss[256], qq[256];
  ss[t] = s; qq[t] = q;
  __syncthreads();
  for (int off = 128; off > 0; off >>= 1) {
    if (t < off) { ss[t] += ss[t + off]; qq[t] += qq[t + off]; }
    __syncthreads();
  }
  if (t == 0) {
    float m = ss[0] / cnt;
    float v = qq[0] / cnt - m * m;
    float r = rsqrtf(v + 1e-5f);
    float scl = r * g[c];
    int o = c + (br2 ? 256 : 0);
    sc[o] = scl;
    sh[o] = b[c] - m * scl;
  }
}

// ============ BN apply, branch-merged ============
template <bool RELU, bool OUTF32>
__global__ void bn_apply_k(const unsigned short* __restrict__ x, void* __restrict__ y,
                           const float* __restrict__ sc, const float* __restrict__ sh,
                           int C, long t81, long t82, long xOff2, long yOff2q4) {
  long i = (long)blockIdx.x * blockDim.x + threadIdx.x;
  if (i >= t81 + t82) return;
  const bool br2 = i >= t81;
  const long ii = br2 ? i - t81 : i;
  const int scO = br2 ? 256 : 0;
  const uint4 v = ((const uint4*)x + (br2 ? xOff2 : 0))[ii];
  int c0 = (int)((ii * 8) % C);
  const float4 s0 = *(const float4*)&sc[scO + c0];
  const float4 s1 = *(const float4*)&sc[scO + c0 + 4];
  const float4 h0 = *(const float4*)&sh[scO + c0];
  const float4 h1 = *(const float4*)&sh[scO + c0 + 4];
  float f[8];
  f[0] = h2f((unsigned short)(v.x & 0xffff)); f[1] = h2f((unsigned short)(v.x >> 16));
  f[2] = h2f((unsigned short)(v.y & 0xffff)); f[3] = h2f((unsigned short)(v.y >> 16));
  f[4] = h2f((unsigned short)(v.z & 0xffff)); f[5] = h2f((unsigned short)(v.z >> 16));
  f[6] = h2f((unsigned short)(v.w & 0xffff)); f[7] = h2f((unsigned short)(v.w >> 16));
  const float S[8] = {s0.x, s0.y, s0.z, s0.w, s1.x, s1.y, s1.z, s1.w};
  const float H[8] = {h0.x, h0.y, h0.z, h0.w, h1.x, h1.y, h1.z, h1.w};
#pragma unroll
  for (int j = 0; j < 8; ++j) {
    f[j] = fmaf(f[j], S[j], H[j]);
    if (RELU) f[j] = fmaxf(f[j], 0.f);
  }
  if (OUTF32) {
    float4* yb = (float4*)y + (br2 ? yOff2q4 : 0);
    float4 o0 = {f[0], f[1], f[2], f[3]}, o1 = {f[4], f[5], f[6], f[7]};
    yb[2 * ii] = o0;
    yb[2 * ii + 1] = o1;
  } else {
    uint4 o;
    o.x = (unsigned)f2h(f[0]) | ((unsigned)f2h(f[1]) << 16);
    o.y = (unsigned)f2h(f[2]) | ((unsigned)f2h(f[3]) << 16);
    o.z = (unsigned)f2h(f[4]) | ((unsigned)f2h(f[5]) << 16);
    o.w = (unsigned)f2h(f[6]) | ((unsigned)f2h(f[7]) << 16);
    ((uint4*)y + (br2 ? xOff2 : 0))[ii] = o;
  }
}

// ============ fused BN+ReLU+MaxPool 3x3 s2, branch-merged ============
__global__ void bn_pool_k(const unsigned short* __restrict__ in, unsigned short* __restrict__ out,
                          const float* __restrict__ sc, const float* __restrict__ sh,
                          int C8, int Hi1, int Ho1, long t81, long inOff2, long outOff2,
                          int Hi2, int Ho2, long t82) {
  long i = (long)blockIdx.x * blockDim.x + threadIdx.x;
  if (i >= t81 + t82) return;
  const bool br2 = i >= t81;
  const long ii = br2 ? i - t81 : i;
  const int Hi = br2 ? Hi2 : Hi1, Wi = Hi;
  const int Ho = br2 ? Ho2 : Ho1, Wo = Ho;
  const int scO = br2 ? 256 : 0;
  const uint4* inB = (const uint4*)in + (br2 ? inOff2 : 0);
  uint4* outB = (uint4*)out + (br2 ? outOff2 : 0);
  int cg = (int)(ii % C8);
  long r = ii / C8;
  int ox = (int)(r % Wo);
  r /= Wo;
  int oy = (int)(r % Ho);
  int n = (int)(r / Ho);
  const int c0 = cg * 8;
  const float4 s0 = *(const float4*)&sc[scO + c0];
  const float4 s1 = *(const float4*)&sc[scO + c0 + 4];
  const float4 h0 = *(const float4*)&sh[scO + c0];
  const float4 h1 = *(const float4*)&sh[scO + c0 + 4];
  const float S[8] = {s0.x, s0.y, s0.z, s0.w, s1.x, s1.y, s1.z, s1.w};
  const float H[8] = {h0.x, h0.y, h0.z, h0.w, h1.x, h1.y, h1.z, h1.w};
  const uint4* bp = inB + ((long)(n * Hi + 2 * oy) * Wi + 2 * ox) * C8 + cg;
  float m[8];
#pragma unroll
  for (int j = 0; j < 8; ++j) m[j] = -3.4e38f;
#pragma unroll
  for (int dy = 0; dy < 3; ++dy)
#pragma unroll
    for (int dx = 0; dx < 3; ++dx) {
      const uint4 v = bp[((long)dy * Wi + dx) * C8];
      float f[8];
      f[0] = h2f((unsigned short)(v.x & 0xffff)); f[1] = h2f((unsigned short)(v.x >> 16));
      f[2] = h2f((unsigned short)(v.y & 0xffff)); f[3] = h2f((unsigned short)(v.y >> 16));
      f[4] = h2f((unsigned short)(v.z & 0xffff)); f[5] = h2f((unsigned short)(v.z >> 16));
      f[6] = h2f((unsigned short)(v.w & 0xffff)); f[7] = h2f((unsigned short)(v.w >> 16));
#pragma unroll
      for (int j = 0; j < 8; ++j) {
        f[j] = fmaxf(fmaf(f[j], S[j], H[j]), 0.f);
        m[j] = fmaxf(m[j], f[j]);
      }
    }
  uint4 o;
  o.x = (unsigned)f2h(m[0]) | ((unsigned)f2h(m[1]) << 16);
  o.y = (unsigned)f2h(m[2]) | ((unsigned)f2h(m[3]) << 16);
  o.z = (unsigned)f2h(m[4]) | ((unsigned)f2h(m[5]) << 16);
  o.w = (unsigned)f2h(m[6]) | ((unsigned)f2h(m[7]) << 16);
  outB[ii] = o;
}

// ============ cross-correlation ============
__global__ void xcorr_part(const float* __restrict__ o1, const float* __restrict__ o2,
                           float* __restrict__ part) {
  const int p = blockIdx.x;
  const int b = blockIdx.y;
  const int oy = p / 17, ox = p - (p / 17) * 17;
  const float* o1b = o1 + (long)b * 22 * 22 * 128;
  const float* o2b = o2 + (long)b * 4608;
  float acc = 0.f;
  for (int i = threadIdx.x; i < 4608; i += 256) {
    int c = i & 127;
    int r = i >> 7;
    int kx = r % 6, ky = r / 6;
    acc = fmaf(o1b[((oy + ky) * 22 + ox + kx) * 128 + c], o2b[i], acc);
  }
#pragma unroll
  for (int off = 32; off > 0; off >>= 1) acc += __shfl_down(acc, off, 64);
  __shared__ float sh[4];
  const int lane = threadIdx.x & 63, wid = threadIdx.x >> 6;
  if (lane == 0) sh[wid] = acc;
  __syncthreads();
  if (threadIdx.x == 0) part[p * 32 + b] = sh[0] + sh[1] + sh[2] + sh[3];
}

__global__ void xcorr_out(const float* __restrict__ part, float* __restrict__ out, int total) {
  int i = blockIdx.x * 256 + threadIdx.x;
  if (i >= total) return;
  int p = i % 289;
  float s = 0.f;
  for (int b = 0; b < 32; ++b) s += part[p * 32 + b];
  out[i] = s * (1.f / 147456.f);
}

// ============ host ============
extern "C" void kernel_launch(void* const* d_in, const int* in_sizes, int n_in,
                              void* d_out, int out_size, void* d_ws, size_t ws_size,
                              hipStream_t stream) {
  (void)in_sizes; (void)n_in; (void)ws_size; (void)out_size;
  const float* input1 = (const float*)d_in[0];
  const float* input2 = (const float*)d_in[1];
  const float* cw[5];
  const float* bg[5];
  const float* bb[5];
  for (int i = 0; i < 5; ++i) {
    cw[i] = (const float*)d_in[2 + 2 * i];
    bg[i] = (const float*)d_in[12 + 2 * i];
    bb[i] = (const float*)d_in[13 + 2 * i];
  }
  const int H1a = 123, P1a = 61, H2a = 57, P2a = 28, H3a = 26, H4a = 24, H5a = 22;
  const int H1b = 59, P1b = 29, H2b = 25, P2b = 12, H3b = 10, H4b = 8, H5b = 6;
  auto NP = [](int h) { return 32 * h * h; };
  const int NP1a = NP(H1a), NP1b = NP(H1b);
  const int NP2a = NP(H2a), NP2b = NP(H2b);
  const int NP3a = NP(H3a), NP3b = NP(H3b);
  const int NP4a = NP(H4a), NP4b = NP(H4b);
  const int NP5a = NP(H5a), NP5b = NP(H5b);
  auto BX = [](int np) { return (np + 127) / 128; };

  char* p = (char*)d_ws;
  auto alloc = [&](size_t bytes) {
    char* r = p;
    p += (bytes + 255) & ~(size_t)255;
    return r;
  };
  unsigned short* P = (unsigned short*)alloc(((size_t)NP1a + NP1b) * 96 * 2);
  unsigned short* R = (unsigned short*)alloc(((size_t)NP(P1a) + NP(P1b)) * 96 * 2 + 262144);
  unsigned short* Q = (unsigned short*)alloc(((size_t)NP4a + NP4b) * 192 * 2);
  float* O12 = (float*)alloc(((size_t)NP5a + NP5b) * 128 * 4);
  unsigned short* I12h = (unsigned short*)alloc(((size_t)32 * 255 * 255 * 4 + (size_t)32 * 127 * 127 * 4) * 2 + 65536);
  unsigned short* W1h = (unsigned short*)alloc(17l * 128 * 32 * 2);
  unsigned short* W2 = (unsigned short*)alloc(25l * 256 * 96 * 2);
  unsigned short* W3 = (unsigned short*)alloc(9l * 192 * 256 * 2);
  unsigned short* W4 = (unsigned short*)alloc(9l * 192 * 192 * 2);
  unsigned short* W5 = (unsigned short*)alloc(9l * 128 * 192 * 2);
  float* part = (float*)alloc(9000000);
  float* sc = (float*)alloc(512 * 4);
  float* sh = (float*)alloc(512 * 4);
  float* O1 = O12;
  float* O2 = O12 + (size_t)NP5a * 128;

  // merged prep (inputs + all weights)
  {
    long in_tot = 32l * 255 * 255 + 32l * 127 * 127;
    long wt_tot = 17l * 128 * 32 + 25l * 256 * 96 + 9l * 192 * 256 + 9l * 192 * 192 + 9l * 128 * 192;
    long tot = in_tot + wt_tot;
    prep_all<<<(unsigned)((tot + 255) / 256), 256, 0, stream>>>(
        input1, input2, I12h, I12h + 32l * 255 * 255 * 4,
        cw[0], cw[1], cw[2], cw[3], cw[4], W1h, W2, W3, W4, W5);
  }

  // ---- layer 1 (96-co tiles) ----
  {
    int BX1 = BX(NP1a), BXt = BX1 + BX(NP1b);
    conv1_mfma<<<(unsigned)BXt, 256, 0, stream>>>(I12h, W1h, P, part,
        255, H1a, NP1a, BX1, 32l * 255 * 255 * 4, (long)NP1a * 96,
        127, H1b, NP1b);
    bn_finalize<<<192, 256, 0, stream>>>(part, bg[0], bb[0], sc, sh, 96, BX1, BXt,
                                         (float)NP1a, (float)NP1b);
    long t81 = (long)NP(P1a) * 96 / 8, t82 = (long)NP(P1b) * 96 / 8;
    bn_pool_k<<<(unsigned)((t81 + t82 + 255) / 256), 256, 0, stream>>>(
        P, R, sc, sh, 12, H1a, P1a, t81, (long)NP1a * 96 / 8, t81, H1b, P1b, t82);
  }
  // ---- layer 2 (1D grid, co fast) ----
  {
    int BX1 = BX(NP2a), BXt = BX1 + BX(NP2b);
    conv_mfma<5, 4, 2><<<(unsigned)(BXt * 2), 256, 0, stream>>>(R, W2, P, part, 96, 256, 256,
        P1a, H2a, NP2a, BX1, (long)NP(P1a) * 96, (long)NP2a * 256,
        P1b, H2b, NP2b);
    bn_finalize<<<512, 256, 0, stream>>>(part, bg[1], bb[1], sc, sh, 256, BX1, BXt,
                                         (float)NP2a, (float)NP2b);
    long t81 = (long)NP(P2a) * 256 / 8, t82 = (long)NP(P2b) * 256 / 8;
    bn_pool_k<<<(unsigned)((t81 + t82 + 255) / 256), 256, 0, stream>>>(
        P, R, sc, sh, 32, H2a, P2a, t81, (long)NP2a * 256 / 8, t81, H2b, P2b, t82);
  }
  // ---- layer 3 (96-co tiles, Co_pad 192) ----
  {
    int BX1 = BX(NP3a), BXt = BX1 + BX(NP3b);
    conv_mfma<3, 3, 2><<<(unsigned)(BXt * 2), 256, 0, stream>>>(R, W3, P, part, 256, 192, 192,
        P2a, H3a, NP3a, BX1, (long)NP(P2a) * 256, (long)NP3a * 192,
        P2b, H3b, NP3b);
    bn_finalize<<<384, 256, 0, stream>>>(part, bg[2], bb[2], sc, sh, 192, BX1, BXt,
                                         (float)NP3a, (float)NP3b);
    long t81 = (long)NP3a * 192 / 8, t82 = (long)NP3b * 192 / 8;
    bn_apply_k<true, false><<<(unsigned)((t81 + t82 + 255) / 256), 256, 0, stream>>>(
        P, P, sc, sh, 192, t81, t82, t81, 0);
  }
  // ---- layer 4 (96-co tiles, Co_pad 192) ----
  {
    int BX1 = BX(NP4a), BXt = BX1 + BX(NP4b);
    conv_mfma<3, 3, 2><<<(unsigned)(BXt * 2), 256, 0, stream>>>(P, W4, Q, part, 192, 192, 192,
        H3a, H4a, NP4a, BX1, (long)NP3a * 192, (long)NP4a * 192,
        H3b, H4b, NP4b);
    bn_finalize<<<384, 256, 0, stream>>>(part, bg[3], bb[3], sc, sh, 192, BX1, BXt,
                                         (float)NP4a, (float)NP4b);
    long t81 = (long)NP4a * 192 / 8, t82 = (long)NP4b * 192 / 8;
    bn_apply_k<true, false><<<(unsigned)((t81 + t82 + 255) / 256), 256, 0, stream>>>(
        Q, Q, sc, sh, 192, t81, t82, t81, 0);
  }
  // ---- layer 5 ----
  {
    int BX1 = BX(NP5a), BXt = BX1 + BX(NP5b);
    conv_mfma<3, 4, 1><<<(unsigned)BXt, 256, 0, stream>>>(Q, W5, P, part, 192, 128, 128,
        H4a, H5a, NP5a, BX1, (long)NP4a * 192, (long)NP5a * 128,
        H4b, H5b, NP5b);
    bn_finalize<<<256, 256, 0, stream>>>(part, bg[4], bb[4], sc, sh, 128, BX1, BXt,
                                         (float)NP5a, (float)NP5b);
    long t81 = (long)NP5a * 128 / 8, t82 = (long)NP5b * 128 / 8;
    bn_apply_k<false, true><<<(unsigned)((t81 + t82 + 255) / 256), 256, 0, stream>>>(
        P, O12, sc, sh, 128, t81, t82, t81, (long)NP5a * 128 / 4);
  }

  xcorr_part<<<dim3(289, 32), 256, 0, stream>>>(O1, O2, part);
  xcorr_out<<<(9248 + 255) / 256, 256, 0, stream>>>(part, (float*)d_out, 9248);
}